// Round 1
// baseline (19870.125 us; speedup 1.0000x reference)
//
#include <hip/hip_runtime.h>
#include <cmath>

#define N_NODES 50000
#define N_EDGES 800000
#define IN_DIM 1024
#define HID 512
#define N_CLASSES 6
#define N_GRAPHS 8
#define NEG_SLOPE 0.2f

// ---------- helpers ----------
__device__ inline void atomicMaxF(float* addr, float val) {
    // Works when *addr is initialized to -inf and holds valid floats.
    if (val >= 0.f) atomicMax((int*)addr, __float_as_int(val));
    else            atomicMin((unsigned int*)addr, (unsigned int)__float_as_int(val));
}

// ---------- GEMM: C[M,512] = A[M,K] @ B[K,512], f32, 64x64 tile ----------
__global__ __launch_bounds__(256) void gemm_f32(const float* __restrict__ A,
                                                const float* __restrict__ B,
                                                float* __restrict__ C,
                                                int M, int K) {
    __shared__ float As[16][68];  // [k][row] (A tile transposed at write)
    __shared__ float Bs[16][68];  // [k][col]
    const int tid = threadIdx.x;
    const int tx = tid & 15, ty = tid >> 4;
    const int rowBase = blockIdx.y * 64, colBase = blockIdx.x * 64;
    const int lr = tid >> 2;          // 0..63 : A-tile row this thread loads
    const int lk = (tid & 3) * 4;     // k-part
    const int bk = tid >> 4;          // 0..15 : B-tile k-row
    const int bc = (tid & 15) * 4;    // col-part
    float acc[4][4] = {};
    for (int kk = 0; kk < K; kk += 16) {
        float4 a4 = make_float4(0.f, 0.f, 0.f, 0.f);
        int ar = rowBase + lr;
        if (ar < M) a4 = *(const float4*)(A + (size_t)ar * K + kk + lk);
        float4 b4 = *(const float4*)(B + (size_t)(kk + bk) * HID + colBase + bc);
        As[lk + 0][lr] = a4.x; As[lk + 1][lr] = a4.y;
        As[lk + 2][lr] = a4.z; As[lk + 3][lr] = a4.w;
        *(float4*)&Bs[bk][bc] = b4;
        __syncthreads();
#pragma unroll
        for (int k = 0; k < 16; ++k) {
            float4 av = *(const float4*)&As[k][ty * 4];
            float4 bv = *(const float4*)&Bs[k][tx * 4];
            float a[4] = {av.x, av.y, av.z, av.w};
            float b[4] = {bv.x, bv.y, bv.z, bv.w};
#pragma unroll
            for (int i = 0; i < 4; ++i)
#pragma unroll
                for (int j = 0; j < 4; ++j)
                    acc[i][j] = fmaf(a[i], b[j], acc[i][j]);
        }
        __syncthreads();
    }
#pragma unroll
    for (int i = 0; i < 4; ++i) {
        int r = rowBase + ty * 4 + i;
        if (r < M) {
            float4 o = make_float4(acc[i][0], acc[i][1], acc[i][2], acc[i][3]);
            *(float4*)(C + (size_t)r * HID + colBase + tx * 4) = o;
        }
    }
}

// ---------- per-node attention dots: a_s[n]=h[n].as, a_d[n]=h[n].ad ----------
__global__ __launch_bounds__(128) void adot_kernel(const float* __restrict__ h,
                                                   const float* __restrict__ att_s,
                                                   const float* __restrict__ att_d,
                                                   float* __restrict__ a_s,
                                                   float* __restrict__ a_d) {
    int n = blockIdx.x;
    int t = threadIdx.x;  // 128 threads * 4 floats = 512
    float4 v  = ((const float4*)(h + (size_t)n * HID))[t];
    float4 vs = ((const float4*)att_s)[t];
    float4 vd = ((const float4*)att_d)[t];
    float ss = v.x * vs.x + v.y * vs.y + v.z * vs.z + v.w * vs.w;
    float sd = v.x * vd.x + v.y * vd.y + v.z * vd.z + v.w * vd.w;
#pragma unroll
    for (int off = 32; off; off >>= 1) {
        ss += __shfl_down(ss, off);
        sd += __shfl_down(sd, off);
    }
    __shared__ float red[4];
    if ((t & 63) == 0) { red[(t >> 6) * 2] = ss; red[(t >> 6) * 2 + 1] = sd; }
    __syncthreads();
    if (t == 0) { a_s[n] = red[0] + red[2]; a_d[n] = red[1] + red[3]; }
}

// ---------- init m=-inf, denom=0 ----------
__global__ void init_layer_kernel(float* __restrict__ m, float* __restrict__ denom) {
    int i = blockIdx.x * blockDim.x + threadIdx.x;
    if (i < N_NODES) { m[i] = -__builtin_inff(); denom[i] = 0.f; }
}

// ---------- edge pass 1: e = leakyrelu(a_s[src]+a_d[dst]); segment max ----------
__global__ void edge_max_kernel(const int* __restrict__ src, const int* __restrict__ dst,
                                const float* __restrict__ a_s, const float* __restrict__ a_d,
                                float* __restrict__ e, float* __restrict__ m) {
    int i = blockIdx.x * blockDim.x + threadIdx.x;
    if (i >= N_EDGES) return;
    int s = src[i], d = dst[i];
    float v = a_s[s] + a_d[d];
    v = v > 0.f ? v : NEG_SLOPE * v;
    e[i] = v;
    atomicMaxF(m + d, v);
}

// ---------- edge pass 2: ex = exp(e - m[dst]); segment sum ----------
__global__ void edge_exp_kernel(const int* __restrict__ dst, const float* __restrict__ m,
                                float* __restrict__ e, float* __restrict__ denom) {
    int i = blockIdx.x * blockDim.x + threadIdx.x;
    if (i >= N_EDGES) return;
    int d = dst[i];
    float ex = expf(e[i] - m[d]);
    e[i] = ex;
    atomicAdd(denom + d, ex);
}

// ---------- edge pass 3: acc[dst] += alpha * h[src] (one wave per edge) ----------
__global__ __launch_bounds__(256) void aggregate_kernel(const int* __restrict__ src,
                                                        const int* __restrict__ dst,
                                                        const float* __restrict__ ex,
                                                        const float* __restrict__ denom,
                                                        const float* __restrict__ h,
                                                        float* __restrict__ acc) {
    int wave = threadIdx.x >> 6;
    int lane = threadIdx.x & 63;
    int edge = blockIdx.x * 4 + wave;
    if (edge >= N_EDGES) return;
    int s = src[edge], d = dst[edge];
    float alpha = ex[edge] / (denom[d] + 1e-16f);
    const float4* hp = (const float4*)(h + (size_t)s * HID);
    float* ap = acc + (size_t)d * HID;
#pragma unroll
    for (int r = 0; r < 2; ++r) {
        int c = lane + r * 64;        // float4 index 0..127
        float4 v = hp[c];
        atomicAdd(ap + c * 4 + 0, alpha * v.x);
        atomicAdd(ap + c * 4 + 1, alpha * v.y);
        atomicAdd(ap + c * 4 + 2, alpha * v.z);
        atomicAdd(ap + c * 4 + 3, alpha * v.w);
    }
}

// ---------- bias + optional relu (in place over [N,512]) ----------
__global__ void bias_act_kernel(float* __restrict__ x, const float* __restrict__ bias,
                                int do_relu) {
    size_t i = (size_t)blockIdx.x * blockDim.x + threadIdx.x;  // float4 index
    if (i >= (size_t)N_NODES * HID / 4) return;
    float4 v = ((float4*)x)[i];
    int c = (int)((i * 4) & (HID - 1));
    const float4 b = *(const float4*)(bias + c);
    v.x += b.x; v.y += b.y; v.z += b.z; v.w += b.w;
    if (do_relu) {
        v.x = fmaxf(v.x, 0.f); v.y = fmaxf(v.y, 0.f);
        v.z = fmaxf(v.z, 0.f); v.w = fmaxf(v.w, 0.f);
    }
    ((float4*)x)[i] = v;
}

// ---------- pooled init ----------
__global__ void init_pooled_kernel(float* __restrict__ pooled) {
    int i = blockIdx.x * blockDim.x + threadIdx.x;
    if (i < N_GRAPHS * HID) pooled[i] = -__builtin_inff();
}

// ---------- global max pool ----------
__global__ __launch_bounds__(128) void pool_kernel(const float* __restrict__ X,
                                                   const int* __restrict__ batch,
                                                   float* __restrict__ pooled) {
    int n = blockIdx.x;
    int t = threadIdx.x;
    int g = batch[n];
    float4 v = ((const float4*)(X + (size_t)n * HID))[t];
    float* pp = pooled + (size_t)g * HID + t * 4;
    atomicMaxF(pp + 0, v.x);
    atomicMaxF(pp + 1, v.y);
    atomicMaxF(pp + 2, v.z);
    atomicMaxF(pp + 3, v.w);
}

// ---------- final tiny linear: out[8,6] = pooled[8,512] @ Wlin[512,6] + blin ----------
__global__ __launch_bounds__(64) void final_linear_kernel(const float* __restrict__ pooled,
                                                          const float* __restrict__ Wlin,
                                                          const float* __restrict__ blin,
                                                          float* __restrict__ out) {
    int t = threadIdx.x;
    if (t >= N_GRAPHS * N_CLASSES) return;
    int g = t / N_CLASSES, c = t % N_CLASSES;
    float s = blin[c];
    for (int k = 0; k < HID; ++k)
        s = fmaf(pooled[(size_t)g * HID + k], Wlin[(size_t)k * N_CLASSES + c], s);
    out[t] = s;
}

// ---------- launch ----------
extern "C" void kernel_launch(void* const* d_in, const int* in_sizes, int n_in,
                              void* d_out, int out_size, void* d_ws, size_t ws_size,
                              hipStream_t stream) {
    const float* x       = (const float*)d_in[0];
    const int*   eidx    = (const int*)d_in[1];
    const int*   batch   = (const int*)d_in[2];
    const float* W[3]    = {(const float*)d_in[3], (const float*)d_in[7], (const float*)d_in[11]};
    const float* Asrc[3] = {(const float*)d_in[4], (const float*)d_in[8], (const float*)d_in[12]};
    const float* Adst[3] = {(const float*)d_in[5], (const float*)d_in[9], (const float*)d_in[13]};
    const float* Bias[3] = {(const float*)d_in[6], (const float*)d_in[10], (const float*)d_in[14]};
    const float* Wlin    = (const float*)d_in[15];
    const float* blin    = (const float*)d_in[16];
    const int* src = eidx;              // edge_index[0]
    const int* dst = eidx + N_EDGES;    // edge_index[1]

    float* bufH   = (float*)d_ws;                       // [N,512]
    float* bufX   = bufH + (size_t)N_NODES * HID;       // [N,512]
    float* a_s    = bufX + (size_t)N_NODES * HID;       // [N]
    float* a_d    = a_s + N_NODES;                      // [N]
    float* mbuf   = a_d + N_NODES;                      // [N]
    float* dbuf   = mbuf + N_NODES;                     // [N]
    float* ebuf   = dbuf + N_NODES;                     // [E]
    float* pooled = ebuf + N_EDGES;                     // [8,512]

    dim3 gemm_grid(HID / 64, (N_NODES + 63) / 64);
    int edge_blocks = (N_EDGES + 255) / 256;

    for (int l = 0; l < 3; ++l) {
        const float* Xin = (l == 0) ? x : bufX;
        int K = (l == 0) ? IN_DIM : HID;
        gemm_f32<<<gemm_grid, 256, 0, stream>>>(Xin, W[l], bufH, N_NODES, K);
        adot_kernel<<<N_NODES, 128, 0, stream>>>(bufH, Asrc[l], Adst[l], a_s, a_d);
        init_layer_kernel<<<(N_NODES + 255) / 256, 256, 0, stream>>>(mbuf, dbuf);
        hipMemsetAsync(bufX, 0, (size_t)N_NODES * HID * sizeof(float), stream);
        edge_max_kernel<<<edge_blocks, 256, 0, stream>>>(src, dst, a_s, a_d, ebuf, mbuf);
        edge_exp_kernel<<<edge_blocks, 256, 0, stream>>>(dst, mbuf, ebuf, dbuf);
        aggregate_kernel<<<(N_EDGES + 3) / 4, 256, 0, stream>>>(src, dst, ebuf, dbuf, bufH, bufX);
        bias_act_kernel<<<(int)(((size_t)N_NODES * HID / 4 + 255) / 256), 256, 0, stream>>>(
            bufX, Bias[l], (l < 2) ? 1 : 0);
    }
    init_pooled_kernel<<<(N_GRAPHS * HID + 255) / 256, 256, 0, stream>>>(pooled);
    pool_kernel<<<N_NODES, 128, 0, stream>>>(bufX, batch, pooled);
    final_linear_kernel<<<1, 64, 0, stream>>>(pooled, Wlin, blin, (float*)d_out);
}

// Round 2
// 5006.316 us; speedup vs baseline: 3.9690x; 3.9690x over previous
//
#include <hip/hip_runtime.h>
#include <cmath>

#define N_NODES 50000
#define N_EDGES 800000
#define IN_DIM 1024
#define HID 512
#define N_CLASSES 6
#define N_GRAPHS 8
#define NEG_SLOPE 0.2f
#define SCAN_BLK 256
#define N_SCAN_BLOCKS ((N_NODES + SCAN_BLK - 1) / SCAN_BLK)   // 196

// ---------- helpers ----------
__device__ inline void atomicMaxF(float* addr, float val) {
    if (val >= 0.f) atomicMax((int*)addr, __float_as_int(val));
    else            atomicMin((unsigned int*)addr, (unsigned int)__float_as_int(val));
}

// ---------- GEMM: C[M,512] = A[M,K] @ B[K,512], f32, 64x64 tile ----------
__global__ __launch_bounds__(256) void gemm_f32(const float* __restrict__ A,
                                                const float* __restrict__ B,
                                                float* __restrict__ C,
                                                int M, int K) {
    __shared__ float As[16][68];
    __shared__ float Bs[16][68];
    const int tid = threadIdx.x;
    const int tx = tid & 15, ty = tid >> 4;
    const int rowBase = blockIdx.y * 64, colBase = blockIdx.x * 64;
    const int lr = tid >> 2;
    const int lk = (tid & 3) * 4;
    const int bk = tid >> 4;
    const int bc = (tid & 15) * 4;
    float acc[4][4] = {};
    for (int kk = 0; kk < K; kk += 16) {
        float4 a4 = make_float4(0.f, 0.f, 0.f, 0.f);
        int ar = rowBase + lr;
        if (ar < M) a4 = *(const float4*)(A + (size_t)ar * K + kk + lk);
        float4 b4 = *(const float4*)(B + (size_t)(kk + bk) * HID + colBase + bc);
        As[lk + 0][lr] = a4.x; As[lk + 1][lr] = a4.y;
        As[lk + 2][lr] = a4.z; As[lk + 3][lr] = a4.w;
        *(float4*)&Bs[bk][bc] = b4;
        __syncthreads();
#pragma unroll
        for (int k = 0; k < 16; ++k) {
            float4 av = *(const float4*)&As[k][ty * 4];
            float4 bv = *(const float4*)&Bs[k][tx * 4];
            float a[4] = {av.x, av.y, av.z, av.w};
            float b[4] = {bv.x, bv.y, bv.z, bv.w};
#pragma unroll
            for (int i = 0; i < 4; ++i)
#pragma unroll
                for (int j = 0; j < 4; ++j)
                    acc[i][j] = fmaf(a[i], b[j], acc[i][j]);
        }
        __syncthreads();
    }
#pragma unroll
    for (int i = 0; i < 4; ++i) {
        int r = rowBase + ty * 4 + i;
        if (r < M) {
            float4 o = make_float4(acc[i][0], acc[i][1], acc[i][2], acc[i][3]);
            *(float4*)(C + (size_t)r * HID + colBase + tx * 4) = o;
        }
    }
}

// ---------- per-node attention dots ----------
__global__ __launch_bounds__(128) void adot_kernel(const float* __restrict__ h,
                                                   const float* __restrict__ att_s,
                                                   const float* __restrict__ att_d,
                                                   float* __restrict__ a_s,
                                                   float* __restrict__ a_d) {
    int n = blockIdx.x;
    int t = threadIdx.x;
    float4 v  = ((const float4*)(h + (size_t)n * HID))[t];
    float4 vs = ((const float4*)att_s)[t];
    float4 vd = ((const float4*)att_d)[t];
    float ss = v.x * vs.x + v.y * vs.y + v.z * vs.z + v.w * vs.w;
    float sd = v.x * vd.x + v.y * vd.y + v.z * vd.z + v.w * vd.w;
#pragma unroll
    for (int off = 32; off; off >>= 1) {
        ss += __shfl_down(ss, off);
        sd += __shfl_down(sd, off);
    }
    __shared__ float red[4];
    if ((t & 63) == 0) { red[(t >> 6) * 2] = ss; red[(t >> 6) * 2 + 1] = sd; }
    __syncthreads();
    if (t == 0) { a_s[n] = red[0] + red[2]; a_d[n] = red[1] + red[3]; }
}

// ================= CSR build (once per call) =================
__global__ void count_kernel(const int* __restrict__ dst, int* __restrict__ cnt) {
    int i = blockIdx.x * blockDim.x + threadIdx.x;
    if (i < N_EDGES) atomicAdd(cnt + dst[i], 1);
}

// exclusive scan within 256-block; emit block totals
__global__ __launch_bounds__(SCAN_BLK) void scan1_kernel(const int* __restrict__ cnt,
                                                         int* __restrict__ partial,
                                                         int* __restrict__ blocksum) {
    __shared__ int tmp[SCAN_BLK];
    int t = threadIdx.x;
    int i = blockIdx.x * SCAN_BLK + t;
    int v = (i < N_NODES) ? cnt[i] : 0;
    tmp[t] = v;
    __syncthreads();
    for (int off = 1; off < SCAN_BLK; off <<= 1) {
        int u = (t >= off) ? tmp[t - off] : 0;
        __syncthreads();
        tmp[t] += u;
        __syncthreads();
    }
    if (i < N_NODES) partial[i] = tmp[t] - v;   // exclusive
    if (t == SCAN_BLK - 1) blocksum[blockIdx.x] = tmp[t];
}

// exclusive scan of the 196 block sums (single block)
__global__ __launch_bounds__(SCAN_BLK) void scan2_kernel(int* __restrict__ blocksum) {
    __shared__ int tmp[SCAN_BLK];
    int t = threadIdx.x;
    int v = (t < N_SCAN_BLOCKS) ? blocksum[t] : 0;
    tmp[t] = v;
    __syncthreads();
    for (int off = 1; off < SCAN_BLK; off <<= 1) {
        int u = (t >= off) ? tmp[t - off] : 0;
        __syncthreads();
        tmp[t] += u;
        __syncthreads();
    }
    if (t < N_SCAN_BLOCKS) blocksum[t] = tmp[t] - v;
}

__global__ __launch_bounds__(SCAN_BLK) void scan3_kernel(const int* __restrict__ partial,
                                                         const int* __restrict__ blocksum,
                                                         int* __restrict__ rowptr,
                                                         int* __restrict__ cursor) {
    int i = blockIdx.x * SCAN_BLK + threadIdx.x;
    if (i < N_NODES) {
        int r = partial[i] + blocksum[blockIdx.x];
        rowptr[i] = r;
        cursor[i] = r;
    }
    if (i == 0) rowptr[N_NODES] = N_EDGES;
}

// scatter src ids into dst-sorted order
__global__ void scatter_kernel(const int* __restrict__ src, const int* __restrict__ dst,
                               int* __restrict__ cursor, int* __restrict__ src_s) {
    int i = blockIdx.x * blockDim.x + threadIdx.x;
    if (i >= N_EDGES) return;
    int p = atomicAdd(cursor + dst[i], 1);
    src_s[p] = src[i];
}

// ========== fused per-node online-softmax aggregation (no atomics) ==========
// one wave per destination node; acc held in 8 registers (2 float4 per lane)
__global__ __launch_bounds__(256) void aggregate_fused(const int* __restrict__ rowptr,
                                                       const int* __restrict__ src_s,
                                                       const float* __restrict__ a_s,
                                                       const float* __restrict__ a_d,
                                                       const float* __restrict__ h,
                                                       const float* __restrict__ bias,
                                                       int do_relu,
                                                       float* __restrict__ outx) {
    int wave = threadIdx.x >> 6;
    int lane = threadIdx.x & 63;
    int n = blockIdx.x * 4 + wave;
    if (n >= N_NODES) return;
    int beg = rowptr[n], end = rowptr[n + 1];
    float a_dn = a_d[n];
    float m = -__builtin_inff();
    float ssum = 0.f;
    float4 acc0 = make_float4(0.f, 0.f, 0.f, 0.f);
    float4 acc1 = make_float4(0.f, 0.f, 0.f, 0.f);
    for (int j = beg; j < end; ++j) {
        int s = src_s[j];
        float v = a_s[s] + a_dn;
        v = v > 0.f ? v : NEG_SLOPE * v;
        float mn = fmaxf(m, v);
        float scale = __expf(m - mn);    // 0 on first edge (m = -inf), 1 if max unchanged
        float p = __expf(v - mn);
        ssum = ssum * scale + p;
        m = mn;
        const float4* hp = (const float4*)(h + (size_t)s * HID);
        float4 v0 = hp[lane];
        float4 v1 = hp[lane + 64];
        acc0.x = fmaf(p, v0.x, acc0.x * scale);
        acc0.y = fmaf(p, v0.y, acc0.y * scale);
        acc0.z = fmaf(p, v0.z, acc0.z * scale);
        acc0.w = fmaf(p, v0.w, acc0.w * scale);
        acc1.x = fmaf(p, v1.x, acc1.x * scale);
        acc1.y = fmaf(p, v1.y, acc1.y * scale);
        acc1.z = fmaf(p, v1.z, acc1.z * scale);
        acc1.w = fmaf(p, v1.w, acc1.w * scale);
    }
    float inv = 1.f / (ssum + 1e-16f);
    const float4 b0 = ((const float4*)bias)[lane];
    const float4 b1 = ((const float4*)bias)[lane + 64];
    float4 o0, o1;
    o0.x = acc0.x * inv + b0.x; o0.y = acc0.y * inv + b0.y;
    o0.z = acc0.z * inv + b0.z; o0.w = acc0.w * inv + b0.w;
    o1.x = acc1.x * inv + b1.x; o1.y = acc1.y * inv + b1.y;
    o1.z = acc1.z * inv + b1.z; o1.w = acc1.w * inv + b1.w;
    if (do_relu) {
        o0.x = fmaxf(o0.x, 0.f); o0.y = fmaxf(o0.y, 0.f);
        o0.z = fmaxf(o0.z, 0.f); o0.w = fmaxf(o0.w, 0.f);
        o1.x = fmaxf(o1.x, 0.f); o1.y = fmaxf(o1.y, 0.f);
        o1.z = fmaxf(o1.z, 0.f); o1.w = fmaxf(o1.w, 0.f);
    }
    float4* op = (float4*)(outx + (size_t)n * HID);
    op[lane] = o0;
    op[lane + 64] = o1;
}

// ---------- pooled init ----------
__global__ void init_pooled_kernel(float* __restrict__ pooled) {
    int i = blockIdx.x * blockDim.x + threadIdx.x;
    if (i < N_GRAPHS * HID) pooled[i] = -__builtin_inff();
}

// ---------- global max pool ----------
__global__ __launch_bounds__(128) void pool_kernel(const float* __restrict__ X,
                                                   const int* __restrict__ batch,
                                                   float* __restrict__ pooled) {
    int n = blockIdx.x;
    int t = threadIdx.x;
    int g = batch[n];
    float4 v = ((const float4*)(X + (size_t)n * HID))[t];
    float* pp = pooled + (size_t)g * HID + t * 4;
    atomicMaxF(pp + 0, v.x);
    atomicMaxF(pp + 1, v.y);
    atomicMaxF(pp + 2, v.z);
    atomicMaxF(pp + 3, v.w);
}

// ---------- final tiny linear ----------
__global__ __launch_bounds__(64) void final_linear_kernel(const float* __restrict__ pooled,
                                                          const float* __restrict__ Wlin,
                                                          const float* __restrict__ blin,
                                                          float* __restrict__ out) {
    int t = threadIdx.x;
    if (t >= N_GRAPHS * N_CLASSES) return;
    int g = t / N_CLASSES, c = t % N_CLASSES;
    float s = blin[c];
    for (int k = 0; k < HID; ++k)
        s = fmaf(pooled[(size_t)g * HID + k], Wlin[(size_t)k * N_CLASSES + c], s);
    out[t] = s;
}

// ---------- launch ----------
extern "C" void kernel_launch(void* const* d_in, const int* in_sizes, int n_in,
                              void* d_out, int out_size, void* d_ws, size_t ws_size,
                              hipStream_t stream) {
    const float* x       = (const float*)d_in[0];
    const int*   eidx    = (const int*)d_in[1];
    const int*   batch   = (const int*)d_in[2];
    const float* W[3]    = {(const float*)d_in[3], (const float*)d_in[7], (const float*)d_in[11]};
    const float* Asrc[3] = {(const float*)d_in[4], (const float*)d_in[8], (const float*)d_in[12]};
    const float* Adst[3] = {(const float*)d_in[5], (const float*)d_in[9], (const float*)d_in[13]};
    const float* Bias[3] = {(const float*)d_in[6], (const float*)d_in[10], (const float*)d_in[14]};
    const float* Wlin    = (const float*)d_in[15];
    const float* blin    = (const float*)d_in[16];
    const int* src = eidx;              // edge_index[0]
    const int* dst = eidx + N_EDGES;    // edge_index[1]

    // workspace layout (4-byte units)
    float* bufH   = (float*)d_ws;                         // [N,512]
    float* bufX   = bufH + (size_t)N_NODES * HID;         // [N,512]
    float* a_s    = bufX + (size_t)N_NODES * HID;         // [N]
    float* a_d    = a_s + N_NODES;                        // [N]
    float* pooled = a_d + N_NODES;                        // [8,512]
    int* cnt      = (int*)(pooled + N_GRAPHS * HID);      // [N]
    int* rowptr   = cnt + N_NODES;                        // [N+1]
    int* cursor   = rowptr + N_NODES + 1;                 // [N]
    int* partial  = cursor + N_NODES;                     // [N]
    int* blocksum = partial + N_NODES;                    // [256]
    int* src_s    = blocksum + 256;                       // [E]

    dim3 gemm_grid(HID / 64, (N_NODES + 63) / 64);
    int edge_blocks = (N_EDGES + 255) / 256;

    // ---- CSR build (edge structure shared by all 3 layers) ----
    hipMemsetAsync(cnt, 0, N_NODES * sizeof(int), stream);
    count_kernel<<<edge_blocks, 256, 0, stream>>>(dst, cnt);
    scan1_kernel<<<N_SCAN_BLOCKS, SCAN_BLK, 0, stream>>>(cnt, partial, blocksum);
    scan2_kernel<<<1, SCAN_BLK, 0, stream>>>(blocksum);
    scan3_kernel<<<N_SCAN_BLOCKS, SCAN_BLK, 0, stream>>>(partial, blocksum, rowptr, cursor);
    scatter_kernel<<<edge_blocks, 256, 0, stream>>>(src, dst, cursor, src_s);

    // ---- 3 GAT layers ----
    for (int l = 0; l < 3; ++l) {
        const float* Xin = (l == 0) ? x : bufX;
        int K = (l == 0) ? IN_DIM : HID;
        gemm_f32<<<gemm_grid, 256, 0, stream>>>(Xin, W[l], bufH, N_NODES, K);
        adot_kernel<<<N_NODES, 128, 0, stream>>>(bufH, Asrc[l], Adst[l], a_s, a_d);
        aggregate_fused<<<(N_NODES + 3) / 4, 256, 0, stream>>>(
            rowptr, src_s, a_s, a_d, bufH, Bias[l], (l < 2) ? 1 : 0, bufX);
    }

    // ---- pool + classifier ----
    init_pooled_kernel<<<(N_GRAPHS * HID + 255) / 256, 256, 0, stream>>>(pooled);
    pool_kernel<<<N_NODES, 128, 0, stream>>>(bufX, batch, pooled);
    final_linear_kernel<<<1, 64, 0, stream>>>(pooled, Wlin, blin, (float*)d_out);
}

// Round 3
// 2282.190 us; speedup vs baseline: 8.7066x; 2.1936x over previous
//
#include <hip/hip_runtime.h>
#include <cmath>

#define N_NODES 50000
#define N_EDGES 800000
#define IN_DIM 1024
#define HID 512
#define N_CLASSES 6
#define N_GRAPHS 8
#define NEG_SLOPE 0.2f
#define SCAN_BLK 256
#define N_SCAN_BLOCKS ((N_NODES + SCAN_BLK - 1) / SCAN_BLK)   // 196
#define POOL_STRIP 256
#define POOL_NBLOCKS ((N_NODES + POOL_STRIP - 1) / POOL_STRIP) // 196

// ---------- GEMM: C[M,512] = A[M,K] @ B[K,512], f32, 64x64 tile ----------
__global__ __launch_bounds__(256) void gemm_f32(const float* __restrict__ A,
                                                const float* __restrict__ B,
                                                float* __restrict__ C,
                                                int M, int K) {
    __shared__ float As[16][68];
    __shared__ float Bs[16][68];
    const int tid = threadIdx.x;
    const int tx = tid & 15, ty = tid >> 4;
    const int rowBase = blockIdx.y * 64, colBase = blockIdx.x * 64;
    const int lr = tid >> 2;
    const int lk = (tid & 3) * 4;
    const int bk = tid >> 4;
    const int bc = (tid & 15) * 4;
    float acc[4][4] = {};
    for (int kk = 0; kk < K; kk += 16) {
        float4 a4 = make_float4(0.f, 0.f, 0.f, 0.f);
        int ar = rowBase + lr;
        if (ar < M) a4 = *(const float4*)(A + (size_t)ar * K + kk + lk);
        float4 b4 = *(const float4*)(B + (size_t)(kk + bk) * HID + colBase + bc);
        As[lk + 0][lr] = a4.x; As[lk + 1][lr] = a4.y;
        As[lk + 2][lr] = a4.z; As[lk + 3][lr] = a4.w;
        *(float4*)&Bs[bk][bc] = b4;
        __syncthreads();
#pragma unroll
        for (int k = 0; k < 16; ++k) {
            float4 av = *(const float4*)&As[k][ty * 4];
            float4 bv = *(const float4*)&Bs[k][tx * 4];
            float a[4] = {av.x, av.y, av.z, av.w};
            float b[4] = {bv.x, bv.y, bv.z, bv.w};
#pragma unroll
            for (int i = 0; i < 4; ++i)
#pragma unroll
                for (int j = 0; j < 4; ++j)
                    acc[i][j] = fmaf(a[i], b[j], acc[i][j]);
        }
        __syncthreads();
    }
#pragma unroll
    for (int i = 0; i < 4; ++i) {
        int r = rowBase + ty * 4 + i;
        if (r < M) {
            float4 o = make_float4(acc[i][0], acc[i][1], acc[i][2], acc[i][3]);
            *(float4*)(C + (size_t)r * HID + colBase + tx * 4) = o;
        }
    }
}

// ---------- per-node attention dots ----------
__global__ __launch_bounds__(128) void adot_kernel(const float* __restrict__ h,
                                                   const float* __restrict__ att_s,
                                                   const float* __restrict__ att_d,
                                                   float* __restrict__ a_s,
                                                   float* __restrict__ a_d) {
    int n = blockIdx.x;
    int t = threadIdx.x;
    float4 v  = ((const float4*)(h + (size_t)n * HID))[t];
    float4 vs = ((const float4*)att_s)[t];
    float4 vd = ((const float4*)att_d)[t];
    float ss = v.x * vs.x + v.y * vs.y + v.z * vs.z + v.w * vs.w;
    float sd = v.x * vd.x + v.y * vd.y + v.z * vd.z + v.w * vd.w;
#pragma unroll
    for (int off = 32; off; off >>= 1) {
        ss += __shfl_down(ss, off);
        sd += __shfl_down(sd, off);
    }
    __shared__ float red[4];
    if ((t & 63) == 0) { red[(t >> 6) * 2] = ss; red[(t >> 6) * 2 + 1] = sd; }
    __syncthreads();
    if (t == 0) { a_s[n] = red[0] + red[2]; a_d[n] = red[1] + red[3]; }
}

// ================= CSR build (once per call) =================
__global__ void count_kernel(const int* __restrict__ dst, int* __restrict__ cnt) {
    int i = blockIdx.x * blockDim.x + threadIdx.x;
    if (i < N_EDGES) atomicAdd(cnt + dst[i], 1);
}

__global__ __launch_bounds__(SCAN_BLK) void scan1_kernel(const int* __restrict__ cnt,
                                                         int* __restrict__ partial,
                                                         int* __restrict__ blocksum) {
    __shared__ int tmp[SCAN_BLK];
    int t = threadIdx.x;
    int i = blockIdx.x * SCAN_BLK + t;
    int v = (i < N_NODES) ? cnt[i] : 0;
    tmp[t] = v;
    __syncthreads();
    for (int off = 1; off < SCAN_BLK; off <<= 1) {
        int u = (t >= off) ? tmp[t - off] : 0;
        __syncthreads();
        tmp[t] += u;
        __syncthreads();
    }
    if (i < N_NODES) partial[i] = tmp[t] - v;   // exclusive
    if (t == SCAN_BLK - 1) blocksum[blockIdx.x] = tmp[t];
}

__global__ __launch_bounds__(SCAN_BLK) void scan2_kernel(int* __restrict__ blocksum) {
    __shared__ int tmp[SCAN_BLK];
    int t = threadIdx.x;
    int v = (t < N_SCAN_BLOCKS) ? blocksum[t] : 0;
    tmp[t] = v;
    __syncthreads();
    for (int off = 1; off < SCAN_BLK; off <<= 1) {
        int u = (t >= off) ? tmp[t - off] : 0;
        __syncthreads();
        tmp[t] += u;
        __syncthreads();
    }
    if (t < N_SCAN_BLOCKS) blocksum[t] = tmp[t] - v;
}

__global__ __launch_bounds__(SCAN_BLK) void scan3_kernel(const int* __restrict__ partial,
                                                         const int* __restrict__ blocksum,
                                                         int* __restrict__ rowptr,
                                                         int* __restrict__ cursor) {
    int i = blockIdx.x * SCAN_BLK + threadIdx.x;
    if (i < N_NODES) {
        int r = partial[i] + blocksum[blockIdx.x];
        rowptr[i] = r;
        cursor[i] = r;
    }
    if (i == 0) rowptr[N_NODES] = N_EDGES;
}

__global__ void scatter_kernel(const int* __restrict__ src, const int* __restrict__ dst,
                               int* __restrict__ cursor, int* __restrict__ src_s) {
    int i = blockIdx.x * blockDim.x + threadIdx.x;
    if (i >= N_EDGES) return;
    int p = atomicAdd(cursor + dst[i], 1);
    src_s[p] = src[i];
}

// ========== fused per-node online-softmax aggregation (no atomics) ==========
__global__ __launch_bounds__(256) void aggregate_fused(const int* __restrict__ rowptr,
                                                       const int* __restrict__ src_s,
                                                       const float* __restrict__ a_s,
                                                       const float* __restrict__ a_d,
                                                       const float* __restrict__ h,
                                                       const float* __restrict__ bias,
                                                       int do_relu,
                                                       float* __restrict__ outx) {
    int wave = threadIdx.x >> 6;
    int lane = threadIdx.x & 63;
    int n = blockIdx.x * 4 + wave;
    if (n >= N_NODES) return;
    int beg = rowptr[n], end = rowptr[n + 1];
    float a_dn = a_d[n];
    float m = -__builtin_inff();
    float ssum = 0.f;
    float4 acc0 = make_float4(0.f, 0.f, 0.f, 0.f);
    float4 acc1 = make_float4(0.f, 0.f, 0.f, 0.f);
    for (int j = beg; j < end; ++j) {
        int s = src_s[j];
        float v = a_s[s] + a_dn;
        v = v > 0.f ? v : NEG_SLOPE * v;
        float mn = fmaxf(m, v);
        float scale = __expf(m - mn);
        float p = __expf(v - mn);
        ssum = ssum * scale + p;
        m = mn;
        const float4* hp = (const float4*)(h + (size_t)s * HID);
        float4 v0 = hp[lane];
        float4 v1 = hp[lane + 64];
        acc0.x = fmaf(p, v0.x, acc0.x * scale);
        acc0.y = fmaf(p, v0.y, acc0.y * scale);
        acc0.z = fmaf(p, v0.z, acc0.z * scale);
        acc0.w = fmaf(p, v0.w, acc0.w * scale);
        acc1.x = fmaf(p, v1.x, acc1.x * scale);
        acc1.y = fmaf(p, v1.y, acc1.y * scale);
        acc1.z = fmaf(p, v1.z, acc1.z * scale);
        acc1.w = fmaf(p, v1.w, acc1.w * scale);
    }
    float inv = 1.f / (ssum + 1e-16f);
    const float4 b0 = ((const float4*)bias)[lane];
    const float4 b1 = ((const float4*)bias)[lane + 64];
    float4 o0, o1;
    o0.x = acc0.x * inv + b0.x; o0.y = acc0.y * inv + b0.y;
    o0.z = acc0.z * inv + b0.z; o0.w = acc0.w * inv + b0.w;
    o1.x = acc1.x * inv + b1.x; o1.y = acc1.y * inv + b1.y;
    o1.z = acc1.z * inv + b1.z; o1.w = acc1.w * inv + b1.w;
    if (do_relu) {
        o0.x = fmaxf(o0.x, 0.f); o0.y = fmaxf(o0.y, 0.f);
        o0.z = fmaxf(o0.z, 0.f); o0.w = fmaxf(o0.w, 0.f);
        o1.x = fmaxf(o1.x, 0.f); o1.y = fmaxf(o1.y, 0.f);
        o1.z = fmaxf(o1.z, 0.f); o1.w = fmaxf(o1.w, 0.f);
    }
    float4* op = (float4*)(outx + (size_t)n * HID);
    op[lane] = o0;
    op[lane + 64] = o1;
}

// ========== atomic-free global max pool (batch is sorted) ==========
// pass 1: each block reduces a 256-node strip; thread t owns float4 column t.
__global__ __launch_bounds__(128) void pool1_kernel(const float* __restrict__ X,
                                                    const int* __restrict__ batch,
                                                    float* __restrict__ partial) {
    const int t = threadIdx.x;
    const int b = blockIdx.x;
    const int n0 = b * POOL_STRIP;
    const int n1 = min(n0 + POOL_STRIP, N_NODES);
    const float NEG = -__builtin_inff();
    const float4 neg4 = make_float4(NEG, NEG, NEG, NEG);
    // init this block's 8 graph slots
#pragma unroll
    for (int g = 0; g < N_GRAPHS; ++g)
        ((float4*)(partial + ((size_t)b * N_GRAPHS + g) * HID))[t] = neg4;
    int gcur = batch[n0];
    float4 m = neg4;
    for (int n = n0; n < n1; ++n) {
        int g = batch[n];              // uniform across block
        if (g != gcur) {               // wave-uniform branch
            ((float4*)(partial + ((size_t)b * N_GRAPHS + gcur) * HID))[t] = m;
            m = neg4;
            gcur = g;
        }
        float4 v = ((const float4*)(X + (size_t)n * HID))[t];
        m.x = fmaxf(m.x, v.x); m.y = fmaxf(m.y, v.y);
        m.z = fmaxf(m.z, v.z); m.w = fmaxf(m.w, v.w);
    }
    ((float4*)(partial + ((size_t)b * N_GRAPHS + gcur) * HID))[t] = m;
}

// pass 2: one block per graph reduces all strip partials.
__global__ __launch_bounds__(128) void pool2_kernel(const float* __restrict__ partial,
                                                    float* __restrict__ pooled) {
    const int g = blockIdx.x;
    const int t = threadIdx.x;
    const float NEG = -__builtin_inff();
    float4 m = make_float4(NEG, NEG, NEG, NEG);
    for (int b = 0; b < POOL_NBLOCKS; ++b) {
        float4 v = ((const float4*)(partial + ((size_t)b * N_GRAPHS + g) * HID))[t];
        m.x = fmaxf(m.x, v.x); m.y = fmaxf(m.y, v.y);
        m.z = fmaxf(m.z, v.z); m.w = fmaxf(m.w, v.w);
    }
    ((float4*)(pooled + (size_t)g * HID))[t] = m;
}

// ---------- final tiny linear ----------
__global__ __launch_bounds__(64) void final_linear_kernel(const float* __restrict__ pooled,
                                                          const float* __restrict__ Wlin,
                                                          const float* __restrict__ blin,
                                                          float* __restrict__ out) {
    int t = threadIdx.x;
    if (t >= N_GRAPHS * N_CLASSES) return;
    int g = t / N_CLASSES, c = t % N_CLASSES;
    float s = blin[c];
    for (int k = 0; k < HID; ++k)
        s = fmaf(pooled[(size_t)g * HID + k], Wlin[(size_t)k * N_CLASSES + c], s);
    out[t] = s;
}

// ---------- launch ----------
extern "C" void kernel_launch(void* const* d_in, const int* in_sizes, int n_in,
                              void* d_out, int out_size, void* d_ws, size_t ws_size,
                              hipStream_t stream) {
    const float* x       = (const float*)d_in[0];
    const int*   eidx    = (const int*)d_in[1];
    const int*   batch   = (const int*)d_in[2];
    const float* W[3]    = {(const float*)d_in[3], (const float*)d_in[7], (const float*)d_in[11]};
    const float* Asrc[3] = {(const float*)d_in[4], (const float*)d_in[8], (const float*)d_in[12]};
    const float* Adst[3] = {(const float*)d_in[5], (const float*)d_in[9], (const float*)d_in[13]};
    const float* Bias[3] = {(const float*)d_in[6], (const float*)d_in[10], (const float*)d_in[14]};
    const float* Wlin    = (const float*)d_in[15];
    const float* blin    = (const float*)d_in[16];
    const int* src = eidx;              // edge_index[0]
    const int* dst = eidx + N_EDGES;    // edge_index[1]

    // workspace layout (4-byte units)
    float* bufH   = (float*)d_ws;                         // [N,512]  (h; reused as pool partials)
    float* bufX   = bufH + (size_t)N_NODES * HID;         // [N,512]
    float* a_s    = bufX + (size_t)N_NODES * HID;         // [N]
    float* a_d    = a_s + N_NODES;                        // [N]
    float* pooled = a_d + N_NODES;                        // [8,512]
    int* cnt      = (int*)(pooled + N_GRAPHS * HID);      // [N]
    int* rowptr   = cnt + N_NODES;                        // [N+1]
    int* cursor   = rowptr + N_NODES + 1;                 // [N]
    int* partial  = cursor + N_NODES;                     // [N]
    int* blocksum = partial + N_NODES;                    // [256]
    int* src_s    = blocksum + 256;                       // [E]

    dim3 gemm_grid(HID / 64, (N_NODES + 63) / 64);
    int edge_blocks = (N_EDGES + 255) / 256;

    // ---- CSR build (edge structure shared by all 3 layers) ----
    hipMemsetAsync(cnt, 0, N_NODES * sizeof(int), stream);
    count_kernel<<<edge_blocks, 256, 0, stream>>>(dst, cnt);
    scan1_kernel<<<N_SCAN_BLOCKS, SCAN_BLK, 0, stream>>>(cnt, partial, blocksum);
    scan2_kernel<<<1, SCAN_BLK, 0, stream>>>(blocksum);
    scan3_kernel<<<N_SCAN_BLOCKS, SCAN_BLK, 0, stream>>>(partial, blocksum, rowptr, cursor);
    scatter_kernel<<<edge_blocks, 256, 0, stream>>>(src, dst, cursor, src_s);

    // ---- 3 GAT layers ----
    for (int l = 0; l < 3; ++l) {
        const float* Xin = (l == 0) ? x : bufX;
        int K = (l == 0) ? IN_DIM : HID;
        gemm_f32<<<gemm_grid, 256, 0, stream>>>(Xin, W[l], bufH, N_NODES, K);
        adot_kernel<<<N_NODES, 128, 0, stream>>>(bufH, Asrc[l], Adst[l], a_s, a_d);
        aggregate_fused<<<(N_NODES + 3) / 4, 256, 0, stream>>>(
            rowptr, src_s, a_s, a_d, bufH, Bias[l], (l < 2) ? 1 : 0, bufX);
    }

    // ---- pool + classifier (atomic-free; bufH is free here, reuse for partials) ----
    float* pool_partial = bufH;   // [196][8][512] floats = 3.2 MB << bufH
    pool1_kernel<<<POOL_NBLOCKS, 128, 0, stream>>>(bufX, batch, pool_partial);
    pool2_kernel<<<N_GRAPHS, 128, 0, stream>>>(pool_partial, pooled);
    final_linear_kernel<<<1, 64, 0, stream>>>(pooled, Wlin, blin, (float*)d_out);
}

// Round 4
// 1317.175 us; speedup vs baseline: 15.0854x; 1.7326x over previous
//
#include <hip/hip_runtime.h>
#include <cmath>

#define N_NODES 50000
#define N_EDGES 800000
#define IN_DIM 1024
#define HID 512
#define N_CLASSES 6
#define N_GRAPHS 8
#define NEG_SLOPE 0.2f
#define SCAN_BLK 256
#define N_SCAN_BLOCKS ((N_NODES + SCAN_BLK - 1) / SCAN_BLK)   // 196
#define POOL_STRIP 256
#define POOL_NBLOCKS ((N_NODES + POOL_STRIP - 1) / POOL_STRIP) // 196

typedef _Float16 half8 __attribute__((ext_vector_type(8)));
typedef float floatx4 __attribute__((ext_vector_type(4)));

// ---------- W transpose + cast: W[K][512] f32 -> Wt[512][K] f16 ----------
__global__ __launch_bounds__(256) void transpose_cast_W(const float* __restrict__ W,
                                                        _Float16* __restrict__ Wt,
                                                        int K) {
    __shared__ float sh[32][33];
    const int kb = blockIdx.x * 32, nb = blockIdx.y * 32;
    const int tx = threadIdx.x & 31, ty = threadIdx.x >> 5;   // ty 0..7
#pragma unroll
    for (int i = 0; i < 32; i += 8)
        sh[ty + i][tx] = W[(size_t)(kb + ty + i) * HID + nb + tx];
    __syncthreads();
#pragma unroll
    for (int i = 0; i < 32; i += 8)
        Wt[(size_t)(nb + ty + i) * K + kb + tx] = (_Float16)sh[tx][ty + i];
}

// ---------- MFMA GEMM: C[M,512] = A[M,K](f32, cast in-flight) @ Bt[512,K]^T ----------
// 128x128 tile, 4 waves (2x2), BK=32, v_mfma_f32_16x16x32_f16
__global__ __launch_bounds__(256) void gemm_mfma_f16(const float* __restrict__ A,
                                                     const _Float16* __restrict__ Bt,
                                                     float* __restrict__ C,
                                                     int M, int K) {
    const int tid  = threadIdx.x;
    const int lane = tid & 63;
    const int wave = tid >> 6;                 // 0..3
    const int wm = wave >> 1, wn = wave & 1;   // 2x2 wave grid, 64x64 each
    const int rowBase = blockIdx.y * 128;
    const int colBase = blockIdx.x * 128;

    __shared__ _Float16 As[128][40];   // row stride 80B (16B-aligned, 2-way conflicts only)
    __shared__ _Float16 Bs[128][40];

    const int srow  = tid >> 1;            // staging row 0..127
    const int shalf = (tid & 1) * 16;      // f16 start index 0/16

    const int fr = lane & 15;              // fragment row/col
    const int kc = lane >> 4;              // k-chunk 0..3

    floatx4 acc[4][4] = {};

    int arow = rowBase + srow; if (arow >= M) arow = M - 1;   // clamp (dup rows, writes guarded)
    const float*    aRow = A  + (size_t)arow * K + shalf;
    const _Float16* bRow = Bt + (size_t)(colBase + srow) * K + shalf;

    for (int kb = 0; kb < K; kb += 32) {
        // ---- stage A: 16 f32 -> 16 f16 per thread ----
        const float* ap = aRow + kb;
        float4 af0 = *(const float4*)(ap + 0);
        float4 af1 = *(const float4*)(ap + 4);
        float4 af2 = *(const float4*)(ap + 8);
        float4 af3 = *(const float4*)(ap + 12);
        union { _Float16 h[16]; half8 v[2]; } au;
        au.h[0]  = (_Float16)af0.x; au.h[1]  = (_Float16)af0.y;
        au.h[2]  = (_Float16)af0.z; au.h[3]  = (_Float16)af0.w;
        au.h[4]  = (_Float16)af1.x; au.h[5]  = (_Float16)af1.y;
        au.h[6]  = (_Float16)af1.z; au.h[7]  = (_Float16)af1.w;
        au.h[8]  = (_Float16)af2.x; au.h[9]  = (_Float16)af2.y;
        au.h[10] = (_Float16)af2.z; au.h[11] = (_Float16)af2.w;
        au.h[12] = (_Float16)af3.x; au.h[13] = (_Float16)af3.y;
        au.h[14] = (_Float16)af3.z; au.h[15] = (_Float16)af3.w;
        half8* dstA = (half8*)&As[srow][shalf];
        // ---- stage B (already f16) ----
        const _Float16* bp = bRow + kb;
        half8 b0 = *(const half8*)bp;
        half8 b1 = *(const half8*)(bp + 8);
        half8* dstB = (half8*)&Bs[srow][shalf];
        dstA[0] = au.v[0]; dstA[1] = au.v[1];
        dstB[0] = b0;      dstB[1] = b1;
        __syncthreads();

        // ---- fragments + 16 MFMA ----
        half8 afr[4], bfr[4];
#pragma unroll
        for (int mi = 0; mi < 4; ++mi)
            afr[mi] = *(const half8*)&As[wm * 64 + mi * 16 + fr][kc * 8];
#pragma unroll
        for (int ni = 0; ni < 4; ++ni)
            bfr[ni] = *(const half8*)&Bs[wn * 64 + ni * 16 + fr][kc * 8];
#pragma unroll
        for (int mi = 0; mi < 4; ++mi)
#pragma unroll
            for (int ni = 0; ni < 4; ++ni)
                acc[mi][ni] = __builtin_amdgcn_mfma_f32_16x16x32_f16(
                    afr[mi], bfr[ni], acc[mi][ni], 0, 0, 0);
        __syncthreads();
    }

    // ---- C write: col = lane&15, row = (lane>>4)*4 + j ----
#pragma unroll
    for (int mi = 0; mi < 4; ++mi) {
#pragma unroll
        for (int ni = 0; ni < 4; ++ni) {
            int col = colBase + wn * 64 + ni * 16 + fr;
#pragma unroll
            for (int j = 0; j < 4; ++j) {
                int row = rowBase + wm * 64 + mi * 16 + kc * 4 + j;
                if (row < M) C[(size_t)row * HID + col] = acc[mi][ni][j];
            }
        }
    }
}

// ---------- per-node attention dots ----------
__global__ __launch_bounds__(128) void adot_kernel(const float* __restrict__ h,
                                                   const float* __restrict__ att_s,
                                                   const float* __restrict__ att_d,
                                                   float* __restrict__ a_s,
                                                   float* __restrict__ a_d) {
    int n = blockIdx.x;
    int t = threadIdx.x;
    float4 v  = ((const float4*)(h + (size_t)n * HID))[t];
    float4 vs = ((const float4*)att_s)[t];
    float4 vd = ((const float4*)att_d)[t];
    float ss = v.x * vs.x + v.y * vs.y + v.z * vs.z + v.w * vs.w;
    float sd = v.x * vd.x + v.y * vd.y + v.z * vd.z + v.w * vd.w;
#pragma unroll
    for (int off = 32; off; off >>= 1) {
        ss += __shfl_down(ss, off);
        sd += __shfl_down(sd, off);
    }
    __shared__ float red[4];
    if ((t & 63) == 0) { red[(t >> 6) * 2] = ss; red[(t >> 6) * 2 + 1] = sd; }
    __syncthreads();
    if (t == 0) { a_s[n] = red[0] + red[2]; a_d[n] = red[1] + red[3]; }
}

// ================= CSR build (once per call) =================
__global__ void count_kernel(const int* __restrict__ dst, int* __restrict__ cnt) {
    int i = blockIdx.x * blockDim.x + threadIdx.x;
    if (i < N_EDGES) atomicAdd(cnt + dst[i], 1);
}

__global__ __launch_bounds__(SCAN_BLK) void scan1_kernel(const int* __restrict__ cnt,
                                                         int* __restrict__ partial,
                                                         int* __restrict__ blocksum) {
    __shared__ int tmp[SCAN_BLK];
    int t = threadIdx.x;
    int i = blockIdx.x * SCAN_BLK + t;
    int v = (i < N_NODES) ? cnt[i] : 0;
    tmp[t] = v;
    __syncthreads();
    for (int off = 1; off < SCAN_BLK; off <<= 1) {
        int u = (t >= off) ? tmp[t - off] : 0;
        __syncthreads();
        tmp[t] += u;
        __syncthreads();
    }
    if (i < N_NODES) partial[i] = tmp[t] - v;   // exclusive
    if (t == SCAN_BLK - 1) blocksum[blockIdx.x] = tmp[t];
}

__global__ __launch_bounds__(SCAN_BLK) void scan2_kernel(int* __restrict__ blocksum) {
    __shared__ int tmp[SCAN_BLK];
    int t = threadIdx.x;
    int v = (t < N_SCAN_BLOCKS) ? blocksum[t] : 0;
    tmp[t] = v;
    __syncthreads();
    for (int off = 1; off < SCAN_BLK; off <<= 1) {
        int u = (t >= off) ? tmp[t - off] : 0;
        __syncthreads();
        tmp[t] += u;
        __syncthreads();
    }
    if (t < N_SCAN_BLOCKS) blocksum[t] = tmp[t] - v;
}

__global__ __launch_bounds__(SCAN_BLK) void scan3_kernel(const int* __restrict__ partial,
                                                         const int* __restrict__ blocksum,
                                                         int* __restrict__ rowptr,
                                                         int* __restrict__ cursor) {
    int i = blockIdx.x * SCAN_BLK + threadIdx.x;
    if (i < N_NODES) {
        int r = partial[i] + blocksum[blockIdx.x];
        rowptr[i] = r;
        cursor[i] = r;
    }
    if (i == 0) rowptr[N_NODES] = N_EDGES;
}

__global__ void scatter_kernel(const int* __restrict__ src, const int* __restrict__ dst,
                               int* __restrict__ cursor, int* __restrict__ src_s) {
    int i = blockIdx.x * blockDim.x + threadIdx.x;
    if (i >= N_EDGES) return;
    int p = atomicAdd(cursor + dst[i], 1);
    src_s[p] = src[i];
}

// ========== fused per-node online-softmax aggregation (no atomics) ==========
__global__ __launch_bounds__(256) void aggregate_fused(const int* __restrict__ rowptr,
                                                       const int* __restrict__ src_s,
                                                       const float* __restrict__ a_s,
                                                       const float* __restrict__ a_d,
                                                       const float* __restrict__ h,
                                                       const float* __restrict__ bias,
                                                       int do_relu,
                                                       float* __restrict__ outx) {
    int wave = threadIdx.x >> 6;
    int lane = threadIdx.x & 63;
    int n = blockIdx.x * 4 + wave;
    if (n >= N_NODES) return;
    int beg = rowptr[n], end = rowptr[n + 1];
    float a_dn = a_d[n];
    float m = -__builtin_inff();
    float ssum = 0.f;
    float4 acc0 = make_float4(0.f, 0.f, 0.f, 0.f);
    float4 acc1 = make_float4(0.f, 0.f, 0.f, 0.f);
    for (int j = beg; j < end; ++j) {
        int s = src_s[j];
        float v = a_s[s] + a_dn;
        v = v > 0.f ? v : NEG_SLOPE * v;
        float mn = fmaxf(m, v);
        float scale = __expf(m - mn);
        float p = __expf(v - mn);
        ssum = ssum * scale + p;
        m = mn;
        const float4* hp = (const float4*)(h + (size_t)s * HID);
        float4 v0 = hp[lane];
        float4 v1 = hp[lane + 64];
        acc0.x = fmaf(p, v0.x, acc0.x * scale);
        acc0.y = fmaf(p, v0.y, acc0.y * scale);
        acc0.z = fmaf(p, v0.z, acc0.z * scale);
        acc0.w = fmaf(p, v0.w, acc0.w * scale);
        acc1.x = fmaf(p, v1.x, acc1.x * scale);
        acc1.y = fmaf(p, v1.y, acc1.y * scale);
        acc1.z = fmaf(p, v1.z, acc1.z * scale);
        acc1.w = fmaf(p, v1.w, acc1.w * scale);
    }
    float inv = 1.f / (ssum + 1e-16f);
    const float4 b0 = ((const float4*)bias)[lane];
    const float4 b1 = ((const float4*)bias)[lane + 64];
    float4 o0, o1;
    o0.x = acc0.x * inv + b0.x; o0.y = acc0.y * inv + b0.y;
    o0.z = acc0.z * inv + b0.z; o0.w = acc0.w * inv + b0.w;
    o1.x = acc1.x * inv + b1.x; o1.y = acc1.y * inv + b1.y;
    o1.z = acc1.z * inv + b1.z; o1.w = acc1.w * inv + b1.w;
    if (do_relu) {
        o0.x = fmaxf(o0.x, 0.f); o0.y = fmaxf(o0.y, 0.f);
        o0.z = fmaxf(o0.z, 0.f); o0.w = fmaxf(o0.w, 0.f);
        o1.x = fmaxf(o1.x, 0.f); o1.y = fmaxf(o1.y, 0.f);
        o1.z = fmaxf(o1.z, 0.f); o1.w = fmaxf(o1.w, 0.f);
    }
    float4* op = (float4*)(outx + (size_t)n * HID);
    op[lane] = o0;
    op[lane + 64] = o1;
}

// ========== atomic-free global max pool (batch is sorted) ==========
__global__ __launch_bounds__(128) void pool1_kernel(const float* __restrict__ X,
                                                    const int* __restrict__ batch,
                                                    float* __restrict__ partial) {
    const int t = threadIdx.x;
    const int b = blockIdx.x;
    const int n0 = b * POOL_STRIP;
    const int n1 = min(n0 + POOL_STRIP, N_NODES);
    const float NEG = -__builtin_inff();
    const float4 neg4 = make_float4(NEG, NEG, NEG, NEG);
#pragma unroll
    for (int g = 0; g < N_GRAPHS; ++g)
        ((float4*)(partial + ((size_t)b * N_GRAPHS + g) * HID))[t] = neg4;
    int gcur = batch[n0];
    float4 m = neg4;
    for (int n = n0; n < n1; ++n) {
        int g = batch[n];              // uniform across block
        if (g != gcur) {               // wave-uniform branch
            ((float4*)(partial + ((size_t)b * N_GRAPHS + gcur) * HID))[t] = m;
            m = neg4;
            gcur = g;
        }
        float4 v = ((const float4*)(X + (size_t)n * HID))[t];
        m.x = fmaxf(m.x, v.x); m.y = fmaxf(m.y, v.y);
        m.z = fmaxf(m.z, v.z); m.w = fmaxf(m.w, v.w);
    }
    ((float4*)(partial + ((size_t)b * N_GRAPHS + gcur) * HID))[t] = m;
}

__global__ __launch_bounds__(128) void pool2_kernel(const float* __restrict__ partial,
                                                    float* __restrict__ pooled) {
    const int g = blockIdx.x;
    const int t = threadIdx.x;
    const float NEG = -__builtin_inff();
    float4 m = make_float4(NEG, NEG, NEG, NEG);
    for (int b = 0; b < POOL_NBLOCKS; ++b) {
        float4 v = ((const float4*)(partial + ((size_t)b * N_GRAPHS + g) * HID))[t];
        m.x = fmaxf(m.x, v.x); m.y = fmaxf(m.y, v.y);
        m.z = fmaxf(m.z, v.z); m.w = fmaxf(m.w, v.w);
    }
    ((float4*)(pooled + (size_t)g * HID))[t] = m;
}

// ---------- final tiny linear ----------
__global__ __launch_bounds__(64) void final_linear_kernel(const float* __restrict__ pooled,
                                                          const float* __restrict__ Wlin,
                                                          const float* __restrict__ blin,
                                                          float* __restrict__ out) {
    int t = threadIdx.x;
    if (t >= N_GRAPHS * N_CLASSES) return;
    int g = t / N_CLASSES, c = t % N_CLASSES;
    float s = blin[c];
    for (int k = 0; k < HID; ++k)
        s = fmaf(pooled[(size_t)g * HID + k], Wlin[(size_t)k * N_CLASSES + c], s);
    out[t] = s;
}

// ---------- launch ----------
extern "C" void kernel_launch(void* const* d_in, const int* in_sizes, int n_in,
                              void* d_out, int out_size, void* d_ws, size_t ws_size,
                              hipStream_t stream) {
    const float* x       = (const float*)d_in[0];
    const int*   eidx    = (const int*)d_in[1];
    const int*   batch   = (const int*)d_in[2];
    const float* W[3]    = {(const float*)d_in[3], (const float*)d_in[7], (const float*)d_in[11]};
    const float* Asrc[3] = {(const float*)d_in[4], (const float*)d_in[8], (const float*)d_in[12]};
    const float* Adst[3] = {(const float*)d_in[5], (const float*)d_in[9], (const float*)d_in[13]};
    const float* Bias[3] = {(const float*)d_in[6], (const float*)d_in[10], (const float*)d_in[14]};
    const float* Wlin    = (const float*)d_in[15];
    const float* blin    = (const float*)d_in[16];
    const int* src = eidx;              // edge_index[0]
    const int* dst = eidx + N_EDGES;    // edge_index[1]

    // workspace layout (4-byte units)
    float* bufH   = (float*)d_ws;                         // [N,512]  (h; reused as pool partials)
    float* bufX   = bufH + (size_t)N_NODES * HID;         // [N,512]
    float* a_s    = bufX + (size_t)N_NODES * HID;         // [N]
    float* a_d    = a_s + N_NODES;                        // [N]
    float* pooled = a_d + N_NODES;                        // [8,512]
    int* cnt      = (int*)(pooled + N_GRAPHS * HID);      // [N]
    int* rowptr   = cnt + N_NODES;                        // [N+1]
    int* cursor   = rowptr + N_NODES + 1;                 // [N]
    int* partial  = cursor + N_NODES;                     // [N]
    int* blocksum = partial + N_NODES;                    // [256]
    int* src_s    = blocksum + 256;                       // [E]
    _Float16* Wt  = (_Float16*)(src_s + N_EDGES);         // [512][K] f16, <=1 MB

    int edge_blocks = (N_EDGES + 255) / 256;

    // ---- CSR build (edge structure shared by all 3 layers) ----
    hipMemsetAsync(cnt, 0, N_NODES * sizeof(int), stream);
    count_kernel<<<edge_blocks, 256, 0, stream>>>(dst, cnt);
    scan1_kernel<<<N_SCAN_BLOCKS, SCAN_BLK, 0, stream>>>(cnt, partial, blocksum);
    scan2_kernel<<<1, SCAN_BLK, 0, stream>>>(blocksum);
    scan3_kernel<<<N_SCAN_BLOCKS, SCAN_BLK, 0, stream>>>(partial, blocksum, rowptr, cursor);
    scatter_kernel<<<edge_blocks, 256, 0, stream>>>(src, dst, cursor, src_s);

    // ---- 3 GAT layers ----
    for (int l = 0; l < 3; ++l) {
        const float* Xin = (l == 0) ? x : bufX;
        int K = (l == 0) ? IN_DIM : HID;
        dim3 tgrid(K / 32, HID / 32);
        transpose_cast_W<<<tgrid, 256, 0, stream>>>(W[l], Wt, K);
        dim3 ggrid(HID / 128, (N_NODES + 127) / 128);   // x fastest: col-blocks share A panel
        gemm_mfma_f16<<<ggrid, 256, 0, stream>>>(Xin, Wt, bufH, N_NODES, K);
        adot_kernel<<<N_NODES, 128, 0, stream>>>(bufH, Asrc[l], Adst[l], a_s, a_d);
        aggregate_fused<<<(N_NODES + 3) / 4, 256, 0, stream>>>(
            rowptr, src_s, a_s, a_d, bufH, Bias[l], (l < 2) ? 1 : 0, bufX);
    }

    // ---- pool + classifier (atomic-free; bufH free here, reuse for partials) ----
    float* pool_partial = bufH;   // [196][8][512] floats = 3.2 MB << bufH
    pool1_kernel<<<POOL_NBLOCKS, 128, 0, stream>>>(bufX, batch, pool_partial);
    pool2_kernel<<<N_GRAPHS, 128, 0, stream>>>(pool_partial, pooled);
    final_linear_kernel<<<1, 64, 0, stream>>>(pooled, Wlin, blin, (float*)d_out);
}

// Round 5
// 958.709 us; speedup vs baseline: 20.7259x; 1.3739x over previous
//
#include <hip/hip_runtime.h>
#include <cmath>

#define N_NODES 50000
#define N_EDGES 800000
#define IN_DIM 1024
#define HID 512
#define N_CLASSES 6
#define N_GRAPHS 8
#define NEG_SLOPE 0.2f
#define SCAN_BLK 256
#define N_SCAN_BLOCKS ((N_NODES + SCAN_BLK - 1) / SCAN_BLK)   // 196
#define POOL_STRIP 256
#define POOL_NBLOCKS ((N_NODES + POOL_STRIP - 1) / POOL_STRIP) // 196

typedef _Float16 half8 __attribute__((ext_vector_type(8)));
typedef float floatx4 __attribute__((ext_vector_type(4)));

// ---------- W transpose + cast: W[K][512] f32 -> Wt[512][K] f16 ----------
__global__ __launch_bounds__(256) void transpose_cast_W(const float* __restrict__ W,
                                                        _Float16* __restrict__ Wt,
                                                        int K) {
    __shared__ float sh[32][33];
    const int kb = blockIdx.x * 32, nb = blockIdx.y * 32;
    const int tx = threadIdx.x & 31, ty = threadIdx.x >> 5;   // ty 0..7
#pragma unroll
    for (int i = 0; i < 32; i += 8)
        sh[ty + i][tx] = W[(size_t)(kb + ty + i) * HID + nb + tx];
    __syncthreads();
#pragma unroll
    for (int i = 0; i < 32; i += 8)
        Wt[(size_t)(nb + ty + i) * K + kb + tx] = (_Float16)sh[tx][ty + i];
}

// ---------- MFMA GEMM: C[M,512](f16) = A[M,K](f32, cast in-flight) @ Bt[512,K]^T ----------
// 128x128 tile, 4 waves (2x2), BK=32, v_mfma_f32_16x16x32_f16
__global__ __launch_bounds__(256) void gemm_mfma_f16(const float* __restrict__ A,
                                                     const _Float16* __restrict__ Bt,
                                                     _Float16* __restrict__ C,
                                                     int M, int K) {
    const int tid  = threadIdx.x;
    const int lane = tid & 63;
    const int wave = tid >> 6;                 // 0..3
    const int wm = wave >> 1, wn = wave & 1;   // 2x2 wave grid, 64x64 each
    const int rowBase = blockIdx.y * 128;
    const int colBase = blockIdx.x * 128;

    __shared__ _Float16 As[128][40];   // row stride 80B (16B-aligned, 2-way conflicts only)
    __shared__ _Float16 Bs[128][40];

    const int srow  = tid >> 1;            // staging row 0..127
    const int shalf = (tid & 1) * 16;      // f16 start index 0/16

    const int fr = lane & 15;              // fragment row/col
    const int kc = lane >> 4;              // k-chunk 0..3

    floatx4 acc[4][4] = {};

    int arow = rowBase + srow; if (arow >= M) arow = M - 1;   // clamp (dup rows, writes guarded)
    const float*    aRow = A  + (size_t)arow * K + shalf;
    const _Float16* bRow = Bt + (size_t)(colBase + srow) * K + shalf;

    for (int kb = 0; kb < K; kb += 32) {
        // ---- stage A: 16 f32 -> 16 f16 per thread ----
        const float* ap = aRow + kb;
        float4 af0 = *(const float4*)(ap + 0);
        float4 af1 = *(const float4*)(ap + 4);
        float4 af2 = *(const float4*)(ap + 8);
        float4 af3 = *(const float4*)(ap + 12);
        union { _Float16 h[16]; half8 v[2]; } au;
        au.h[0]  = (_Float16)af0.x; au.h[1]  = (_Float16)af0.y;
        au.h[2]  = (_Float16)af0.z; au.h[3]  = (_Float16)af0.w;
        au.h[4]  = (_Float16)af1.x; au.h[5]  = (_Float16)af1.y;
        au.h[6]  = (_Float16)af1.z; au.h[7]  = (_Float16)af1.w;
        au.h[8]  = (_Float16)af2.x; au.h[9]  = (_Float16)af2.y;
        au.h[10] = (_Float16)af2.z; au.h[11] = (_Float16)af2.w;
        au.h[12] = (_Float16)af3.x; au.h[13] = (_Float16)af3.y;
        au.h[14] = (_Float16)af3.z; au.h[15] = (_Float16)af3.w;
        half8* dstA = (half8*)&As[srow][shalf];
        // ---- stage B (already f16) ----
        const _Float16* bp = bRow + kb;
        half8 b0 = *(const half8*)bp;
        half8 b1 = *(const half8*)(bp + 8);
        half8* dstB = (half8*)&Bs[srow][shalf];
        dstA[0] = au.v[0]; dstA[1] = au.v[1];
        dstB[0] = b0;      dstB[1] = b1;
        __syncthreads();

        // ---- fragments + 16 MFMA ----
        half8 afr[4], bfr[4];
#pragma unroll
        for (int mi = 0; mi < 4; ++mi)
            afr[mi] = *(const half8*)&As[wm * 64 + mi * 16 + fr][kc * 8];
#pragma unroll
        for (int ni = 0; ni < 4; ++ni)
            bfr[ni] = *(const half8*)&Bs[wn * 64 + ni * 16 + fr][kc * 8];
#pragma unroll
        for (int mi = 0; mi < 4; ++mi)
#pragma unroll
            for (int ni = 0; ni < 4; ++ni)
                acc[mi][ni] = __builtin_amdgcn_mfma_f32_16x16x32_f16(
                    afr[mi], bfr[ni], acc[mi][ni], 0, 0, 0);
        __syncthreads();
    }

    // ---- C write (f16): col = lane&15, row = (lane>>4)*4 + j ----
#pragma unroll
    for (int mi = 0; mi < 4; ++mi) {
#pragma unroll
        for (int ni = 0; ni < 4; ++ni) {
            int col = colBase + wn * 64 + ni * 16 + fr;
#pragma unroll
            for (int j = 0; j < 4; ++j) {
                int row = rowBase + wm * 64 + mi * 16 + kc * 4 + j;
                if (row < M) C[(size_t)row * HID + col] = (_Float16)acc[mi][ni][j];
            }
        }
    }
}

// ---------- per-node attention dots (h in fp16; one wave per node) ----------
__global__ __launch_bounds__(256) void adot_kernel(const _Float16* __restrict__ h,
                                                   const float* __restrict__ att_s,
                                                   const float* __restrict__ att_d,
                                                   float* __restrict__ a_s,
                                                   float* __restrict__ a_d) {
    int wave = threadIdx.x >> 6;
    int lane = threadIdx.x & 63;
    int n = blockIdx.x * 4 + wave;
    if (n >= N_NODES) return;
    half8 hv = *(const half8*)(h + (size_t)n * HID + lane * 8);
    float4 s0 = ((const float4*)att_s)[lane * 2];
    float4 s1 = ((const float4*)att_s)[lane * 2 + 1];
    float4 d0 = ((const float4*)att_d)[lane * 2];
    float4 d1 = ((const float4*)att_d)[lane * 2 + 1];
    float hf[8];
#pragma unroll
    for (int q = 0; q < 8; ++q) hf[q] = (float)hv[q];
    float ss = hf[0]*s0.x + hf[1]*s0.y + hf[2]*s0.z + hf[3]*s0.w
             + hf[4]*s1.x + hf[5]*s1.y + hf[6]*s1.z + hf[7]*s1.w;
    float sd = hf[0]*d0.x + hf[1]*d0.y + hf[2]*d0.z + hf[3]*d0.w
             + hf[4]*d1.x + hf[5]*d1.y + hf[6]*d1.z + hf[7]*d1.w;
#pragma unroll
    for (int off = 32; off; off >>= 1) {
        ss += __shfl_down(ss, off);
        sd += __shfl_down(sd, off);
    }
    if (lane == 0) { a_s[n] = ss; a_d[n] = sd; }
}

// ================= CSR build (once per call) =================
__global__ void count_kernel(const int* __restrict__ dst, int* __restrict__ cnt) {
    int i = blockIdx.x * blockDim.x + threadIdx.x;
    if (i < N_EDGES) atomicAdd(cnt + dst[i], 1);
}

__global__ __launch_bounds__(SCAN_BLK) void scan1_kernel(const int* __restrict__ cnt,
                                                         int* __restrict__ partial,
                                                         int* __restrict__ blocksum) {
    __shared__ int tmp[SCAN_BLK];
    int t = threadIdx.x;
    int i = blockIdx.x * SCAN_BLK + t;
    int v = (i < N_NODES) ? cnt[i] : 0;
    tmp[t] = v;
    __syncthreads();
    for (int off = 1; off < SCAN_BLK; off <<= 1) {
        int u = (t >= off) ? tmp[t - off] : 0;
        __syncthreads();
        tmp[t] += u;
        __syncthreads();
    }
    if (i < N_NODES) partial[i] = tmp[t] - v;   // exclusive
    if (t == SCAN_BLK - 1) blocksum[blockIdx.x] = tmp[t];
}

__global__ __launch_bounds__(SCAN_BLK) void scan2_kernel(int* __restrict__ blocksum) {
    __shared__ int tmp[SCAN_BLK];
    int t = threadIdx.x;
    int v = (t < N_SCAN_BLOCKS) ? blocksum[t] : 0;
    tmp[t] = v;
    __syncthreads();
    for (int off = 1; off < SCAN_BLK; off <<= 1) {
        int u = (t >= off) ? tmp[t - off] : 0;
        __syncthreads();
        tmp[t] += u;
        __syncthreads();
    }
    if (t < N_SCAN_BLOCKS) blocksum[t] = tmp[t] - v;
}

__global__ __launch_bounds__(SCAN_BLK) void scan3_kernel(const int* __restrict__ partial,
                                                         const int* __restrict__ blocksum,
                                                         int* __restrict__ rowptr,
                                                         int* __restrict__ cursor) {
    int i = blockIdx.x * SCAN_BLK + threadIdx.x;
    if (i < N_NODES) {
        int r = partial[i] + blocksum[blockIdx.x];
        rowptr[i] = r;
        cursor[i] = r;
    }
    if (i == 0) rowptr[N_NODES] = N_EDGES;
}

__global__ void scatter_kernel(const int* __restrict__ src, const int* __restrict__ dst,
                               int* __restrict__ cursor, int* __restrict__ src_s) {
    int i = blockIdx.x * blockDim.x + threadIdx.x;
    if (i >= N_EDGES) return;
    int p = atomicAdd(cursor + dst[i], 1);
    src_s[p] = src[i];
}

// ========== fused per-node online-softmax aggregation (fp16 h gather) ==========
__global__ __launch_bounds__(256) void aggregate_fused(const int* __restrict__ rowptr,
                                                       const int* __restrict__ src_s,
                                                       const float* __restrict__ a_s,
                                                       const float* __restrict__ a_d,
                                                       const _Float16* __restrict__ h,
                                                       const float* __restrict__ bias,
                                                       int do_relu,
                                                       float* __restrict__ outx) {
    int wave = threadIdx.x >> 6;
    int lane = threadIdx.x & 63;
    int n = blockIdx.x * 4 + wave;
    if (n >= N_NODES) return;
    int beg = rowptr[n], end = rowptr[n + 1];
    float a_dn = a_d[n];
    float m = -__builtin_inff();
    float ssum = 0.f;
    float acc[8] = {};
    for (int j = beg; j < end; ++j) {
        int s = src_s[j];
        float v = a_s[s] + a_dn;
        v = v > 0.f ? v : NEG_SLOPE * v;
        float mn = fmaxf(m, v);
        float scale = __expf(m - mn);   // 0 on first edge, 1 if max unchanged
        float p = __expf(v - mn);
        ssum = ssum * scale + p;
        m = mn;
        half8 hv = *(const half8*)(h + (size_t)s * HID + lane * 8);
#pragma unroll
        for (int q = 0; q < 8; ++q)
            acc[q] = fmaf(p, (float)hv[q], acc[q] * scale);
    }
    float inv = 1.f / (ssum + 1e-16f);
    const float4 b0 = ((const float4*)(bias + lane * 8))[0];
    const float4 b1 = ((const float4*)(bias + lane * 8))[1];
    float4 o0, o1;
    o0.x = acc[0] * inv + b0.x; o0.y = acc[1] * inv + b0.y;
    o0.z = acc[2] * inv + b0.z; o0.w = acc[3] * inv + b0.w;
    o1.x = acc[4] * inv + b1.x; o1.y = acc[5] * inv + b1.y;
    o1.z = acc[6] * inv + b1.z; o1.w = acc[7] * inv + b1.w;
    if (do_relu) {
        o0.x = fmaxf(o0.x, 0.f); o0.y = fmaxf(o0.y, 0.f);
        o0.z = fmaxf(o0.z, 0.f); o0.w = fmaxf(o0.w, 0.f);
        o1.x = fmaxf(o1.x, 0.f); o1.y = fmaxf(o1.y, 0.f);
        o1.z = fmaxf(o1.z, 0.f); o1.w = fmaxf(o1.w, 0.f);
    }
    float4* op = (float4*)(outx + (size_t)n * HID + lane * 8);
    op[0] = o0;
    op[1] = o1;
}

// ========== atomic-free global max pool (batch is sorted) ==========
__global__ __launch_bounds__(128) void pool1_kernel(const float* __restrict__ X,
                                                    const int* __restrict__ batch,
                                                    float* __restrict__ partial) {
    const int t = threadIdx.x;
    const int b = blockIdx.x;
    const int n0 = b * POOL_STRIP;
    const int n1 = min(n0 + POOL_STRIP, N_NODES);
    const float NEG = -__builtin_inff();
    const float4 neg4 = make_float4(NEG, NEG, NEG, NEG);
#pragma unroll
    for (int g = 0; g < N_GRAPHS; ++g)
        ((float4*)(partial + ((size_t)b * N_GRAPHS + g) * HID))[t] = neg4;
    int gcur = batch[n0];
    float4 m = neg4;
    for (int n = n0; n < n1; ++n) {
        int g = batch[n];              // uniform across block
        if (g != gcur) {               // wave-uniform branch
            ((float4*)(partial + ((size_t)b * N_GRAPHS + gcur) * HID))[t] = m;
            m = neg4;
            gcur = g;
        }
        float4 v = ((const float4*)(X + (size_t)n * HID))[t];
        m.x = fmaxf(m.x, v.x); m.y = fmaxf(m.y, v.y);
        m.z = fmaxf(m.z, v.z); m.w = fmaxf(m.w, v.w);
    }
    ((float4*)(partial + ((size_t)b * N_GRAPHS + gcur) * HID))[t] = m;
}

__global__ __launch_bounds__(128) void pool2_kernel(const float* __restrict__ partial,
                                                    float* __restrict__ pooled) {
    const int g = blockIdx.x;
    const int t = threadIdx.x;
    const float NEG = -__builtin_inff();
    float4 m = make_float4(NEG, NEG, NEG, NEG);
    for (int b = 0; b < POOL_NBLOCKS; ++b) {
        float4 v = ((const float4*)(partial + ((size_t)b * N_GRAPHS + g) * HID))[t];
        m.x = fmaxf(m.x, v.x); m.y = fmaxf(m.y, v.y);
        m.z = fmaxf(m.z, v.z); m.w = fmaxf(m.w, v.w);
    }
    ((float4*)(pooled + (size_t)g * HID))[t] = m;
}

// ---------- final tiny linear ----------
__global__ __launch_bounds__(64) void final_linear_kernel(const float* __restrict__ pooled,
                                                          const float* __restrict__ Wlin,
                                                          const float* __restrict__ blin,
                                                          float* __restrict__ out) {
    int t = threadIdx.x;
    if (t >= N_GRAPHS * N_CLASSES) return;
    int g = t / N_CLASSES, c = t % N_CLASSES;
    float s = blin[c];
    for (int k = 0; k < HID; ++k)
        s = fmaf(pooled[(size_t)g * HID + k], Wlin[(size_t)k * N_CLASSES + c], s);
    out[t] = s;
}

// ---------- launch ----------
extern "C" void kernel_launch(void* const* d_in, const int* in_sizes, int n_in,
                              void* d_out, int out_size, void* d_ws, size_t ws_size,
                              hipStream_t stream) {
    const float* x       = (const float*)d_in[0];
    const int*   eidx    = (const int*)d_in[1];
    const int*   batch   = (const int*)d_in[2];
    const float* W[3]    = {(const float*)d_in[3], (const float*)d_in[7], (const float*)d_in[11]};
    const float* Asrc[3] = {(const float*)d_in[4], (const float*)d_in[8], (const float*)d_in[12]};
    const float* Adst[3] = {(const float*)d_in[5], (const float*)d_in[9], (const float*)d_in[13]};
    const float* Bias[3] = {(const float*)d_in[6], (const float*)d_in[10], (const float*)d_in[14]};
    const float* Wlin    = (const float*)d_in[15];
    const float* blin    = (const float*)d_in[16];
    const int* src = eidx;              // edge_index[0]
    const int* dst = eidx + N_EDGES;    // edge_index[1]

    // workspace layout (4-byte units)
    float* bufH   = (float*)d_ws;                         // region: h fp16 lives here; reused for pool partials
    float* bufX   = bufH + (size_t)N_NODES * HID;         // [N,512] f32
    float* a_s    = bufX + (size_t)N_NODES * HID;         // [N]
    float* a_d    = a_s + N_NODES;                        // [N]
    float* pooled = a_d + N_NODES;                        // [8,512]
    int* cnt      = (int*)(pooled + N_GRAPHS * HID);      // [N]
    int* rowptr   = cnt + N_NODES;                        // [N+1]
    int* cursor   = rowptr + N_NODES + 1;                 // [N]
    int* partial  = cursor + N_NODES;                     // [N]
    int* blocksum = partial + N_NODES;                    // [256]
    int* src_s    = blocksum + 256;                       // [E]
    _Float16* Wt  = (_Float16*)(src_s + N_EDGES);         // [512][K] f16, <=1 MB
    _Float16* hH  = (_Float16*)bufH;                      // [N,512] f16 (51 MB, fits bufH region)

    int edge_blocks = (N_EDGES + 255) / 256;

    // ---- CSR build (edge structure shared by all 3 layers) ----
    hipMemsetAsync(cnt, 0, N_NODES * sizeof(int), stream);
    count_kernel<<<edge_blocks, 256, 0, stream>>>(dst, cnt);
    scan1_kernel<<<N_SCAN_BLOCKS, SCAN_BLK, 0, stream>>>(cnt, partial, blocksum);
    scan2_kernel<<<1, SCAN_BLK, 0, stream>>>(blocksum);
    scan3_kernel<<<N_SCAN_BLOCKS, SCAN_BLK, 0, stream>>>(partial, blocksum, rowptr, cursor);
    scatter_kernel<<<edge_blocks, 256, 0, stream>>>(src, dst, cursor, src_s);

    // ---- 3 GAT layers ----
    for (int l = 0; l < 3; ++l) {
        const float* Xin = (l == 0) ? x : bufX;
        int K = (l == 0) ? IN_DIM : HID;
        dim3 tgrid(K / 32, HID / 32);
        transpose_cast_W<<<tgrid, 256, 0, stream>>>(W[l], Wt, K);
        dim3 ggrid(HID / 128, (N_NODES + 127) / 128);   // x fastest: col-blocks share A panel
        gemm_mfma_f16<<<ggrid, 256, 0, stream>>>(Xin, Wt, hH, N_NODES, K);
        adot_kernel<<<(N_NODES + 3) / 4, 256, 0, stream>>>(hH, Asrc[l], Adst[l], a_s, a_d);
        aggregate_fused<<<(N_NODES + 3) / 4, 256, 0, stream>>>(
            rowptr, src_s, a_s, a_d, hH, Bias[l], (l < 2) ? 1 : 0, bufX);
    }

    // ---- pool + classifier (atomic-free; hH region free here, reuse for partials) ----
    float* pool_partial = bufH;   // [196][8][512] floats = 3.2 MB
    pool1_kernel<<<POOL_NBLOCKS, 128, 0, stream>>>(bufX, batch, pool_partial);
    pool2_kernel<<<N_GRAPHS, 128, 0, stream>>>(pool_partial, pooled);
    final_linear_kernel<<<1, 64, 0, stream>>>(pooled, Wlin, blin, (float*)d_out);
}

// Round 6
// 881.212 us; speedup vs baseline: 22.5486x; 1.0879x over previous
//
#include <hip/hip_runtime.h>
#include <cmath>

#define N_NODES 50000
#define N_EDGES 800000
#define IN_DIM 1024
#define HID 512
#define N_CLASSES 6
#define N_GRAPHS 8
#define NEG_SLOPE 0.2f
#define SCAN_BLK 256
#define N_SCAN_BLOCKS ((N_NODES + SCAN_BLK - 1) / SCAN_BLK)   // 196
#define POOL_STRIP 256
#define POOL_NBLOCKS ((N_NODES + POOL_STRIP - 1) / POOL_STRIP) // 196

typedef _Float16 half8 __attribute__((ext_vector_type(8)));
typedef _Float16 half4 __attribute__((ext_vector_type(4)));
typedef float floatx4 __attribute__((ext_vector_type(4)));

// ---------- W transpose + cast: W[K][512] f32 -> Wt[512][K] f16 ----------
__global__ __launch_bounds__(256) void transpose_cast_W(const float* __restrict__ W,
                                                        _Float16* __restrict__ Wt,
                                                        int K) {
    __shared__ float sh[32][33];
    const int kb = blockIdx.x * 32, nb = blockIdx.y * 32;
    const int tx = threadIdx.x & 31, ty = threadIdx.x >> 5;   // ty 0..7
#pragma unroll
    for (int i = 0; i < 32; i += 8)
        sh[ty + i][tx] = W[(size_t)(kb + ty + i) * HID + nb + tx];
    __syncthreads();
#pragma unroll
    for (int i = 0; i < 32; i += 8)
        Wt[(size_t)(nb + ty + i) * K + kb + tx] = (_Float16)sh[tx][ty + i];
}

// ---------- MFMA GEMM: C[M,512](f16) = A[M,K] @ Bt[512,K]^T ----------
// 128x128 tile, 4 waves (2x2), BK=32, v_mfma_f32_16x16x32_f16.
// AT = float (cast in staging) or _Float16 (direct). XCD-bijective block swizzle.
template <typename AT>
__global__ __launch_bounds__(256) void gemm_mfma(const AT* __restrict__ A,
                                                 const _Float16* __restrict__ Bt,
                                                 _Float16* __restrict__ C,
                                                 int M, int K) {
    // ---- bijective XCD swizzle (m204): consecutive logical tiles share an XCD ----
    const int nwg = gridDim.x;
    const int bid = blockIdx.x;
    const int q = nwg >> 3, r = nwg & 7;
    const int xcd = bid & 7, local = bid >> 3;
    const int wgid = (xcd < r) ? xcd * (q + 1) + local
                               : r * (q + 1) + (xcd - r) * q + local;
    const int rowBase = (wgid >> 2) * 128;       // HID/128 = 4 col tiles, x fastest
    const int colBase = (wgid & 3) * 128;

    const int tid  = threadIdx.x;
    const int lane = tid & 63;
    const int wave = tid >> 6;                 // 0..3
    const int wm = wave >> 1, wn = wave & 1;   // 2x2 wave grid, 64x64 each

    __shared__ _Float16 As[128][40];   // row stride 80B: 16B-aligned, ~2-way conflicts
    __shared__ _Float16 Bs[128][40];

    const int srow  = tid >> 1;            // staging row 0..127
    const int shalf = (tid & 1) * 16;      // f16 start index 0/16

    const int fr = lane & 15;              // fragment row/col
    const int kc = lane >> 4;              // k-chunk 0..3

    floatx4 acc[4][4] = {};

    int arow = rowBase + srow; if (arow >= M) arow = M - 1;   // clamp (writes guarded)
    const AT*       aRow = A  + (size_t)arow * K + shalf;
    const _Float16* bRow = Bt + (size_t)(colBase + srow) * K + shalf;

    for (int kb = 0; kb < K; kb += 32) {
        half8* dstA = (half8*)&As[srow][shalf];
        half8* dstB = (half8*)&Bs[srow][shalf];
        if constexpr (sizeof(AT) == 4) {
            // f32 A: load 16 f32, cast to f16 in flight
            const float* ap = (const float*)aRow + kb;
            float4 af0 = *(const float4*)(ap + 0);
            float4 af1 = *(const float4*)(ap + 4);
            float4 af2 = *(const float4*)(ap + 8);
            float4 af3 = *(const float4*)(ap + 12);
            union { _Float16 h[16]; half8 v[2]; } au;
            au.h[0]  = (_Float16)af0.x; au.h[1]  = (_Float16)af0.y;
            au.h[2]  = (_Float16)af0.z; au.h[3]  = (_Float16)af0.w;
            au.h[4]  = (_Float16)af1.x; au.h[5]  = (_Float16)af1.y;
            au.h[6]  = (_Float16)af1.z; au.h[7]  = (_Float16)af1.w;
            au.h[8]  = (_Float16)af2.x; au.h[9]  = (_Float16)af2.y;
            au.h[10] = (_Float16)af2.z; au.h[11] = (_Float16)af2.w;
            au.h[12] = (_Float16)af3.x; au.h[13] = (_Float16)af3.y;
            au.h[14] = (_Float16)af3.z; au.h[15] = (_Float16)af3.w;
            dstA[0] = au.v[0]; dstA[1] = au.v[1];
        } else {
            const _Float16* ap = (const _Float16*)aRow + kb;
            half8 a0 = *(const half8*)ap;
            half8 a1 = *(const half8*)(ap + 8);
            dstA[0] = a0; dstA[1] = a1;
        }
        const _Float16* bp = bRow + kb;
        half8 b0 = *(const half8*)bp;
        half8 b1 = *(const half8*)(bp + 8);
        dstB[0] = b0; dstB[1] = b1;
        __syncthreads();

        // ---- fragments + 16 MFMA ----
        half8 afr[4], bfr[4];
#pragma unroll
        for (int mi = 0; mi < 4; ++mi)
            afr[mi] = *(const half8*)&As[wm * 64 + mi * 16 + fr][kc * 8];
#pragma unroll
        for (int ni = 0; ni < 4; ++ni)
            bfr[ni] = *(const half8*)&Bs[wn * 64 + ni * 16 + fr][kc * 8];
#pragma unroll
        for (int mi = 0; mi < 4; ++mi)
#pragma unroll
            for (int ni = 0; ni < 4; ++ni)
                acc[mi][ni] = __builtin_amdgcn_mfma_f32_16x16x32_f16(
                    afr[mi], bfr[ni], acc[mi][ni], 0, 0, 0);
        __syncthreads();
    }

    // ---- C write (f16): col = lane&15, row = (lane>>4)*4 + j ----
#pragma unroll
    for (int mi = 0; mi < 4; ++mi) {
#pragma unroll
        for (int ni = 0; ni < 4; ++ni) {
            int col = colBase + wn * 64 + ni * 16 + fr;
#pragma unroll
            for (int j = 0; j < 4; ++j) {
                int row = rowBase + wm * 64 + mi * 16 + kc * 4 + j;
                if (row < M) C[(size_t)row * HID + col] = (_Float16)acc[mi][ni][j];
            }
        }
    }
}

// ---------- per-node attention dots (h in fp16; one wave per node) ----------
__global__ __launch_bounds__(256) void adot_kernel(const _Float16* __restrict__ h,
                                                   const float* __restrict__ att_s,
                                                   const float* __restrict__ att_d,
                                                   float* __restrict__ a_s,
                                                   float* __restrict__ a_d) {
    int wave = threadIdx.x >> 6;
    int lane = threadIdx.x & 63;
    int n = blockIdx.x * 4 + wave;
    if (n >= N_NODES) return;
    half8 hv = *(const half8*)(h + (size_t)n * HID + lane * 8);
    float4 s0 = ((const float4*)att_s)[lane * 2];
    float4 s1 = ((const float4*)att_s)[lane * 2 + 1];
    float4 d0 = ((const float4*)att_d)[lane * 2];
    float4 d1 = ((const float4*)att_d)[lane * 2 + 1];
    float hf[8];
#pragma unroll
    for (int q = 0; q < 8; ++q) hf[q] = (float)hv[q];
    float ss = hf[0]*s0.x + hf[1]*s0.y + hf[2]*s0.z + hf[3]*s0.w
             + hf[4]*s1.x + hf[5]*s1.y + hf[6]*s1.z + hf[7]*s1.w;
    float sd = hf[0]*d0.x + hf[1]*d0.y + hf[2]*d0.z + hf[3]*d0.w
             + hf[4]*d1.x + hf[5]*d1.y + hf[6]*d1.z + hf[7]*d1.w;
#pragma unroll
    for (int off = 32; off; off >>= 1) {
        ss += __shfl_down(ss, off);
        sd += __shfl_down(sd, off);
    }
    if (lane == 0) { a_s[n] = ss; a_d[n] = sd; }
}

// ================= CSR build (once per call) =================
__global__ void count_kernel(const int* __restrict__ dst, int* __restrict__ cnt) {
    int i = blockIdx.x * blockDim.x + threadIdx.x;
    if (i < N_EDGES) atomicAdd(cnt + dst[i], 1);
}

__global__ __launch_bounds__(SCAN_BLK) void scan1_kernel(const int* __restrict__ cnt,
                                                         int* __restrict__ partial,
                                                         int* __restrict__ blocksum) {
    __shared__ int tmp[SCAN_BLK];
    int t = threadIdx.x;
    int i = blockIdx.x * SCAN_BLK + t;
    int v = (i < N_NODES) ? cnt[i] : 0;
    tmp[t] = v;
    __syncthreads();
    for (int off = 1; off < SCAN_BLK; off <<= 1) {
        int u = (t >= off) ? tmp[t - off] : 0;
        __syncthreads();
        tmp[t] += u;
        __syncthreads();
    }
    if (i < N_NODES) partial[i] = tmp[t] - v;   // exclusive
    if (t == SCAN_BLK - 1) blocksum[blockIdx.x] = tmp[t];
}

__global__ __launch_bounds__(SCAN_BLK) void scan2_kernel(int* __restrict__ blocksum) {
    __shared__ int tmp[SCAN_BLK];
    int t = threadIdx.x;
    int v = (t < N_SCAN_BLOCKS) ? blocksum[t] : 0;
    tmp[t] = v;
    __syncthreads();
    for (int off = 1; off < SCAN_BLK; off <<= 1) {
        int u = (t >= off) ? tmp[t - off] : 0;
        __syncthreads();
        tmp[t] += u;
        __syncthreads();
    }
    if (t < N_SCAN_BLOCKS) blocksum[t] = tmp[t] - v;
}

__global__ __launch_bounds__(SCAN_BLK) void scan3_kernel(const int* __restrict__ partial,
                                                         const int* __restrict__ blocksum,
                                                         int* __restrict__ rowptr,
                                                         int* __restrict__ cursor) {
    int i = blockIdx.x * SCAN_BLK + threadIdx.x;
    if (i < N_NODES) {
        int r = partial[i] + blocksum[blockIdx.x];
        rowptr[i] = r;
        cursor[i] = r;
    }
    if (i == 0) rowptr[N_NODES] = N_EDGES;
}

__global__ void scatter_kernel(const int* __restrict__ src, const int* __restrict__ dst,
                               int* __restrict__ cursor, int* __restrict__ src_s) {
    int i = blockIdx.x * blockDim.x + threadIdx.x;
    if (i >= N_EDGES) return;
    int p = atomicAdd(cursor + dst[i], 1);
    src_s[p] = src[i];
}

// ========== fused per-node online-softmax aggregation (fp16 h gather, fp16 out) ==========
__global__ __launch_bounds__(256) void aggregate_fused(const int* __restrict__ rowptr,
                                                       const int* __restrict__ src_s,
                                                       const float* __restrict__ a_s,
                                                       const float* __restrict__ a_d,
                                                       const _Float16* __restrict__ h,
                                                       const float* __restrict__ bias,
                                                       int do_relu,
                                                       _Float16* __restrict__ outx) {
    int wave = threadIdx.x >> 6;
    int lane = threadIdx.x & 63;
    int n = blockIdx.x * 4 + wave;
    if (n >= N_NODES) return;
    int beg = rowptr[n], end = rowptr[n + 1];
    float a_dn = a_d[n];
    float m = -__builtin_inff();
    float ssum = 0.f;
    float acc[8] = {};
    for (int j = beg; j < end; ++j) {
        int s = src_s[j];
        float v = a_s[s] + a_dn;
        v = v > 0.f ? v : NEG_SLOPE * v;
        float mn = fmaxf(m, v);
        float scale = __expf(m - mn);   // 0 on first edge, 1 if max unchanged
        float p = __expf(v - mn);
        ssum = ssum * scale + p;
        m = mn;
        half8 hv = *(const half8*)(h + (size_t)s * HID + lane * 8);
#pragma unroll
        for (int q = 0; q < 8; ++q)
            acc[q] = fmaf(p, (float)hv[q], acc[q] * scale);
    }
    float inv = 1.f / (ssum + 1e-16f);
    const float4 b0 = ((const float4*)(bias + lane * 8))[0];
    const float4 b1 = ((const float4*)(bias + lane * 8))[1];
    float o[8];
    o[0] = acc[0] * inv + b0.x; o[1] = acc[1] * inv + b0.y;
    o[2] = acc[2] * inv + b0.z; o[3] = acc[3] * inv + b0.w;
    o[4] = acc[4] * inv + b1.x; o[5] = acc[5] * inv + b1.y;
    o[6] = acc[6] * inv + b1.z; o[7] = acc[7] * inv + b1.w;
    half8 ov;
#pragma unroll
    for (int q = 0; q < 8; ++q) {
        float val = do_relu ? fmaxf(o[q], 0.f) : o[q];
        ov[q] = (_Float16)val;
    }
    *(half8*)(outx + (size_t)n * HID + lane * 8) = ov;
}

// ========== atomic-free global max pool over f16 activations (batch sorted) ==========
__global__ __launch_bounds__(128) void pool1_kernel(const _Float16* __restrict__ X,
                                                    const int* __restrict__ batch,
                                                    float* __restrict__ partial) {
    const int t = threadIdx.x;
    const int b = blockIdx.x;
    const int n0 = b * POOL_STRIP;
    const int n1 = min(n0 + POOL_STRIP, N_NODES);
    const float NEG = -__builtin_inff();
    const float4 neg4 = make_float4(NEG, NEG, NEG, NEG);
#pragma unroll
    for (int g = 0; g < N_GRAPHS; ++g)
        ((float4*)(partial + ((size_t)b * N_GRAPHS + g) * HID))[t] = neg4;
    int gcur = batch[n0];
    float4 m = neg4;
    for (int n = n0; n < n1; ++n) {
        int g = batch[n];              // uniform across block
        if (g != gcur) {               // wave-uniform branch
            ((float4*)(partial + ((size_t)b * N_GRAPHS + gcur) * HID))[t] = m;
            m = neg4;
            gcur = g;
        }
        half4 hv = *(const half4*)(X + (size_t)n * HID + t * 4);
        m.x = fmaxf(m.x, (float)hv[0]); m.y = fmaxf(m.y, (float)hv[1]);
        m.z = fmaxf(m.z, (float)hv[2]); m.w = fmaxf(m.w, (float)hv[3]);
    }
    ((float4*)(partial + ((size_t)b * N_GRAPHS + gcur) * HID))[t] = m;
}

__global__ __launch_bounds__(128) void pool2_kernel(const float* __restrict__ partial,
                                                    float* __restrict__ pooled) {
    const int g = blockIdx.x;
    const int t = threadIdx.x;
    const float NEG = -__builtin_inff();
    float4 m = make_float4(NEG, NEG, NEG, NEG);
    for (int b = 0; b < POOL_NBLOCKS; ++b) {
        float4 v = ((const float4*)(partial + ((size_t)b * N_GRAPHS + g) * HID))[t];
        m.x = fmaxf(m.x, v.x); m.y = fmaxf(m.y, v.y);
        m.z = fmaxf(m.z, v.z); m.w = fmaxf(m.w, v.w);
    }
    ((float4*)(pooled + (size_t)g * HID))[t] = m;
}

// ---------- final tiny linear ----------
__global__ __launch_bounds__(64) void final_linear_kernel(const float* __restrict__ pooled,
                                                          const float* __restrict__ Wlin,
                                                          const float* __restrict__ blin,
                                                          float* __restrict__ out) {
    int t = threadIdx.x;
    if (t >= N_GRAPHS * N_CLASSES) return;
    int g = t / N_CLASSES, c = t % N_CLASSES;
    float s = blin[c];
    for (int k = 0; k < HID; ++k)
        s = fmaf(pooled[(size_t)g * HID + k], Wlin[(size_t)k * N_CLASSES + c], s);
    out[t] = s;
}

// ---------- launch ----------
extern "C" void kernel_launch(void* const* d_in, const int* in_sizes, int n_in,
                              void* d_out, int out_size, void* d_ws, size_t ws_size,
                              hipStream_t stream) {
    const float* x       = (const float*)d_in[0];
    const int*   eidx    = (const int*)d_in[1];
    const int*   batch   = (const int*)d_in[2];
    const float* W[3]    = {(const float*)d_in[3], (const float*)d_in[7], (const float*)d_in[11]};
    const float* Asrc[3] = {(const float*)d_in[4], (const float*)d_in[8], (const float*)d_in[12]};
    const float* Adst[3] = {(const float*)d_in[5], (const float*)d_in[9], (const float*)d_in[13]};
    const float* Bias[3] = {(const float*)d_in[6], (const float*)d_in[10], (const float*)d_in[14]};
    const float* Wlin    = (const float*)d_in[15];
    const float* blin    = (const float*)d_in[16];
    const int* src = eidx;              // edge_index[0]
    const int* dst = eidx + N_EDGES;    // edge_index[1]

    // workspace layout (4-byte units; regions sized as in R1-R4)
    float* bufH   = (float*)d_ws;                         // region A: hH f16 lives here; later pool partials
    float* bufX   = bufH + (size_t)N_NODES * HID;         // region B: activations (f16 now)
    float* a_s    = bufX + (size_t)N_NODES * HID;         // [N]
    float* a_d    = a_s + N_NODES;                        // [N]
    float* pooled = a_d + N_NODES;                        // [8,512]
    int* cnt      = (int*)(pooled + N_GRAPHS * HID);      // [N]
    int* rowptr   = cnt + N_NODES;                        // [N+1]
    int* cursor   = rowptr + N_NODES + 1;                 // [N]
    int* partial  = cursor + N_NODES;                     // [N]
    int* blocksum = partial + N_NODES;                    // [256]
    int* src_s    = blocksum + 256;                       // [E]
    _Float16* Wt  = (_Float16*)(src_s + N_EDGES);         // [512][K] f16, <=1 MB
    _Float16* hH  = (_Float16*)bufH;                      // [N,512] f16 (51 MB)
    _Float16* xAct= (_Float16*)bufX;                      // [N,512] f16 activations (51 MB)

    int edge_blocks = (N_EDGES + 255) / 256;

    // ---- CSR build (edge structure shared by all 3 layers) ----
    hipMemsetAsync(cnt, 0, N_NODES * sizeof(int), stream);
    count_kernel<<<edge_blocks, 256, 0, stream>>>(dst, cnt);
    scan1_kernel<<<N_SCAN_BLOCKS, SCAN_BLK, 0, stream>>>(cnt, partial, blocksum);
    scan2_kernel<<<1, SCAN_BLK, 0, stream>>>(blocksum);
    scan3_kernel<<<N_SCAN_BLOCKS, SCAN_BLK, 0, stream>>>(partial, blocksum, rowptr, cursor);
    scatter_kernel<<<edge_blocks, 256, 0, stream>>>(src, dst, cursor, src_s);

    // ---- 3 GAT layers ----
    const int nrow_tiles = (N_NODES + 127) / 128;     // 391
    const int gemm_blocks = nrow_tiles * (HID / 128); // 1564 (1D, x=col fastest pre-swizzle)
    for (int l = 0; l < 3; ++l) {
        int K = (l == 0) ? IN_DIM : HID;
        dim3 tgrid(K / 32, HID / 32);
        transpose_cast_W<<<tgrid, 256, 0, stream>>>(W[l], Wt, K);
        if (l == 0)
            gemm_mfma<float><<<gemm_blocks, 256, 0, stream>>>(x, Wt, hH, N_NODES, K);
        else
            gemm_mfma<_Float16><<<gemm_blocks, 256, 0, stream>>>(xAct, Wt, hH, N_NODES, K);
        adot_kernel<<<(N_NODES + 3) / 4, 256, 0, stream>>>(hH, Asrc[l], Adst[l], a_s, a_d);
        aggregate_fused<<<(N_NODES + 3) / 4, 256, 0, stream>>>(
            rowptr, src_s, a_s, a_d, hH, Bias[l], (l < 2) ? 1 : 0, xAct);
    }

    // ---- pool + classifier (atomic-free; hH region free here, reuse for partials) ----
    float* pool_partial = bufH;   // [196][8][512] floats = 3.2 MB
    pool1_kernel<<<POOL_NBLOCKS, 128, 0, stream>>>(xAct, batch, pool_partial);
    pool2_kernel<<<N_GRAPHS, 128, 0, stream>>>(pool_partial, pooled);
    final_linear_kernel<<<1, 64, 0, stream>>>(pooled, Wlin, blin, (float*)d_out);
}